// Round 1
// baseline (2064.383 us; speedup 1.0000x reference)
//
#include <hip/hip_runtime.h>
#include <stdint.h>

#define NTOK 1569
#define BB 8
#define CC 768
#define HH 12
#define HD 64
#define NBH (BB*HH)          // 96
#define NROW (NTOK*BB)       // 12552 rows of the [N*B][768] matrices
#define NCHUNK 25            // ceil(1569/64) key chunks
#define NVEC (NBH*NTOK)      // 150624 head-vectors
#define LASTV 33             // valid keys in last chunk: 1569 - 24*64

typedef unsigned short ushort_t;
static const size_t SZ = (size_t)NROW * CC;   // 9,639,936 elems (= NBH*NTOK*HD)

using f32x4 = __attribute__((ext_vector_type(4))) float;
using i32x4 = __attribute__((ext_vector_type(4))) int;
using i32x2 = __attribute__((ext_vector_type(2))) int;
using hfrag = __attribute__((ext_vector_type(8))) _Float16;

// v_exp_f32 computes 2^x; temp is pre-scaled by log2(e) so one trans op/elem.
__device__ __forceinline__ float exp2_fast(float x){
  float r;
  asm("v_exp_f32 %0, %1" : "=v"(r) : "v"(x));
  return r;
}

// ---------------------------------------------------------------------------
// pre[b] = sum_n ||x[n,b,:]||_2  (fp32 input)
// ---------------------------------------------------------------------------
__global__ __launch_bounds__(256) void prenorm_kernel(const float* __restrict__ x,
                                                      float* __restrict__ pre)
{
  const int b = blockIdx.y;
  const int wave = threadIdx.x >> 6, lane = threadIdx.x & 63;
  const int g = blockIdx.x * 4 + wave;          // [0, 200)
  float local = 0.f;
  for (int n = g; n < NTOK; n += 200){
    const float* xp = x + ((size_t)n * BB + b) * CC + lane * 4;
    float ss = 0.f;
    #pragma unroll
    for (int e = 0; e < 3; e++){
      f32x4 vv = *(const f32x4*)(xp + 256*e);
      ss += vv[0]*vv[0] + vv[1]*vv[1] + vv[2]*vv[2] + vv[3]*vv[3];
    }
    #pragma unroll
    for (int off = 1; off < 64; off <<= 1) ss += __shfl_xor(ss, off);
    local += sqrtf(ss);
  }
  if (lane == 0) atomicAdd(&pre[b], local);
}

// ---------------------------------------------------------------------------
// elementwise fp32 -> f16 (RTN), optional scale; n8 = elems/8
// ---------------------------------------------------------------------------
__global__ __launch_bounds__(256) void cvt_f16(const float* __restrict__ in,
                                               ushort_t* __restrict__ out,
                                               int n8, float scl)
{
  const int i = blockIdx.x * 256 + threadIdx.x;
  if (i >= n8) return;
  const float* p = in + (size_t)i * 8;
  f32x4 a = *(const f32x4*)p, b = *(const f32x4*)(p + 4);
  union { _Float16 h[8]; i32x4 v; } u;
  #pragma unroll
  for (int e = 0; e < 4; e++){
    u.h[e]   = (_Float16)(a[e] * scl);
    u.h[4+e] = (_Float16)(b[e] * scl);
  }
  *(i32x4*)(out + (size_t)i * 8) = u.v;
}

// ---------------------------------------------------------------------------
// f16 GEMM: C[m][j] = sum_c A[m][c] * B[j][c];  A [12552][768], B [Nj][768].
// 128x128 tile, BK=64, LDS layout [rowblk][kq][row16][8] (2-way max conflicts).
// mode 0: scatter f16 to q/k/v [B,H,N,64] (Nj=2304)
// mode 1: fp32 out[m*768 + j] + bias[j]       (Nj=768)
// grid: (99, Nj/128), block 256
// ---------------------------------------------------------------------------
__global__ __launch_bounds__(256) void gemm768(
    const ushort_t* __restrict__ A, const ushort_t* __restrict__ Bm,
    ushort_t* __restrict__ q, ushort_t* __restrict__ k, ushort_t* __restrict__ v,
    float* __restrict__ outp, const float* __restrict__ bias, int mode)
{
  __shared__ __align__(16) ushort_t As[8192];  // [rb 0..7][kq 0..7][r16 0..15][8]
  __shared__ __align__(16) ushort_t Bs[8192];

  const int mt = blockIdx.x, jt = blockIdx.y;
  const int tid = threadIdx.x;
  const int w = tid >> 6, lane = tid & 63;
  const int l16 = lane & 15, lq = lane >> 4;

  const int srow = tid & 127, shalf = tid >> 7;       // staging: row + col-half
  int ga = mt*128 + srow; if (ga > NROW-1) ga = NROW-1;
  const ushort_t* ap = A  + (size_t)ga * CC + shalf*32;
  const ushort_t* bp = Bm + (size_t)(jt*128 + srow) * CC + shalf*32;
  const int rb = srow >> 4, r16 = srow & 15;

  const int wr = (w >> 1) * 4, wc = (w & 1) * 4;      // 16-row/col block bases

  f32x4 acc[4][4] = {};
  for (int kt = 0; kt < 12; kt++){
    #pragma unroll
    for (int i = 0; i < 4; i++){
      const int kq = shalf*4 + i;
      *(i32x4*)&As[((rb*8 + kq)*16 + r16)*8] = *(const i32x4*)(ap + kt*64 + i*8);
      *(i32x4*)&Bs[((rb*8 + kq)*16 + r16)*8] = *(const i32x4*)(bp + kt*64 + i*8);
    }
    __syncthreads();
    #pragma unroll
    for (int ks = 0; ks < 2; ks++){
      hfrag af[4], bf[4];
      #pragma unroll
      for (int rt = 0; rt < 4; rt++)
        af[rt] = *(const hfrag*)&As[(((wr+rt)*8 + ks*4 + lq)*16 + l16)*8];
      #pragma unroll
      for (int ct = 0; ct < 4; ct++)
        bf[ct] = *(const hfrag*)&Bs[(((wc+ct)*8 + ks*4 + lq)*16 + l16)*8];
      #pragma unroll
      for (int rt = 0; rt < 4; rt++)
        #pragma unroll
        for (int ct = 0; ct < 4; ct++)
          acc[rt][ct] = __builtin_amdgcn_mfma_f32_16x16x32_f16(af[rt], bf[ct], acc[rt][ct], 0, 0, 0);
    }
    __syncthreads();
  }

  const int mbase = mt*128 + (w >> 1)*64;
  const int jbase = jt*128 + (w & 1)*64;
  #pragma unroll
  for (int ct = 0; ct < 4; ct++){
    const int j = jbase + ct*16 + l16;
    if (mode == 0){
      const int s = j / 768, jj = j - s*768;
      const int h = jj >> 6, d = jj & 63;
      ushort_t* op = (s == 0) ? q : (s == 1) ? k : v;
      #pragma unroll
      for (int rt = 0; rt < 4; rt++)
        #pragma unroll
        for (int r = 0; r < 4; r++){
          const int m = mbase + rt*16 + lq*4 + r;
          if (m < NROW){
            const int n = m >> 3, b = m & 7;
            union { _Float16 h16; ushort_t u; } cv;
            cv.h16 = (_Float16)acc[rt][ct][r];
            op[((size_t)(b*HH + h) * NTOK + n) * HD + d] = cv.u;
          }
        }
    } else {
      const float bv = bias[j];
      #pragma unroll
      for (int rt = 0; rt < 4; rt++)
        #pragma unroll
        for (int r = 0; r < 4; r++){
          const int m = mbase + rt*16 + lq*4 + r;
          if (m < NROW) outp[(size_t)m * CC + j] = acc[rt][ct][r] + bv;
        }
    }
  }
}

// ---------------------------------------------------------------------------
// l2 normalize per head-vector (64 elems), 32 lanes/vector, f16 in/out.
// mode 0: in is [B,H,N,64];  mode 1: in is row-768 layout [(n*8+b)][h*64+d]
// out: [B,H,N,64]
// ---------------------------------------------------------------------------
__global__ __launch_bounds__(256) void l2norm_kernel(const ushort_t* __restrict__ in,
                                                     ushort_t* __restrict__ out,
                                                     int mode)
{
  const int vec = blockIdx.x * 8 + (threadIdx.x >> 5);
  const int lane = threadIdx.x & 31;
  if (vec >= NVEC) return;
  size_t iaddr;
  if (mode == 0){
    iaddr = (size_t)vec * HD + lane*2;
  } else {
    const int b = vec / (HH*NTOK);
    const int rem = vec - b*(HH*NTOK);
    const int h = rem / NTOK, n = rem - h*NTOK;
    iaddr = (size_t)(n*BB + b) * CC + h*HD + lane*2;
  }
  union { ushort_t u[2]; uint32_t pk; _Float16 h[2]; } uv;
  uv.pk = *(const uint32_t*)(in + iaddr);
  const float a = (float)uv.h[0], c = (float)uv.h[1];
  float ss = a*a + c*c;
  #pragma unroll
  for (int off = 1; off < 32; off <<= 1) ss += __shfl_xor(ss, off);
  const float inv = 1.0f / fmaxf(sqrtf(ss), 1e-12f);
  union { _Float16 h[2]; uint32_t pk; } ov;
  ov.h[0] = (_Float16)(a * inv);
  ov.h[1] = (_Float16)(c * inv);
  *(uint32_t*)(out + (size_t)vec * HD + lane*2) = ov.pk;
}

// ---------------------------------------------------------------------------
// MFMA flash attention, transposed-S, max-free softmax (logits provably small).
// X,Y,Z f16 [B,H,N,64]. 128 queries/block (4 waves x 32), 64-key chunks.
//
// This revision:
//  * LDS: stride-64 rows + XOR swizzle (byte ^= (row&7)<<4) for Ks/Vt/Pt ->
//    32 KiB total, bank-conflict-free reads; Vt staging writes rotated by
//    (tid>>3)&7 to break the former 8-way conflict.
//  * XCD-aware block remap: 1248 blocks = 8 XCDs x 156; 156 = 12 bh x 13
//    qblk, so all 13 query-blocks of one (b,h) share an XCD's L2 (K/V reuse).
//  * Async stage split (T14): K/V of chunk ch+1 prefetched into registers
//    during compute of chunk ch; ds_write after the barrier. s-registers
//    shrunk (exp fused per 16-key tile) to pay for the prefetch regs.
//  * exp via single v_exp_f32 (temp pre-scaled by log2 e).
// LDS: Ks 8K + Vt 8K + Pt 16K = 32 KiB.  grid: (13, 96)
// ---------------------------------------------------------------------------
__global__ __launch_bounds__(256, 4) void attn_mfma(
    const ushort_t* __restrict__ X, const ushort_t* __restrict__ Y,
    const ushort_t* __restrict__ Z, void* __restrict__ outp,
    const float* __restrict__ pre, float tf, int mode, int accum)
{
  __shared__ __align__(16) ushort_t Ks[64*64];   // [key][d], swizzled
  __shared__ __align__(16) ushort_t Vt[64*64];   // [d][key], swizzled
  __shared__ __align__(16) ushort_t Pt[128*64];  // [q][key], swizzled

  // XCD-aware remap (bijective: 1248 = 8*156, 156 = 12*13)
  const int lin  = blockIdx.y * 13 + blockIdx.x;
  const int nl   = (lin & 7) * 156 + (lin >> 3);
  const int bh   = nl / 13;
  const int qblk = nl - bh * 13;

  const int b = bh / HH, h = bh - (bh / HH) * HH;
  const float temp = (pre ? pre[b] * tf : tf) * 1.4426950408889634f;
  const size_t base = (size_t)bh * NTOK * HD;
  const int row0 = qblk * 128;
  const int tid = threadIdx.x;
  const int w = tid >> 6, lane = tid & 63;
  const int l16 = lane & 15, lq = lane >> 4;
  const int xk = (l16 & 7) << 4;                 // swizzle key for compute reads

  // Q fragments (b-operand of S^T): rows row0 + w*32 + qt*16 + l16
  hfrag qf[2][2];
  #pragma unroll
  for (int qt = 0; qt < 2; qt++){
    int r = row0 + w*32 + qt*16 + l16; if (r > NTOK-1) r = NTOK-1;
    const ushort_t* qp = X + base + (size_t)r*HD + lq*8;
    qf[qt][0] = *(const hfrag*)qp;
    qf[qt][1] = *(const hfrag*)(qp + 32);
  }

  // staging maps
  const int skey = tid & 63, sseg = tid >> 6;              // K natural
  const int g8 = (tid >> 3) & 7;
  const int vd0 = g8 * 8;                                  // V^T: 8 d-rows
  const int vk0 = (tid & 7) * 2 + sseg * 16;               //      2 keys

  i32x4 kr0, kr1, vr0, vr1;                                // prefetch regs
  auto LOADR = [&](int ch){
    int kg = ch*64 + skey; if (kg > NTOK-1) kg = NTOK-1;
    const ushort_t* kp = Y + base + (size_t)kg*HD + sseg*16;
    kr0 = *(const i32x4*)kp;
    kr1 = *(const i32x4*)(kp + 8);
    int vg0 = ch*64 + vk0, vg1 = vg0 + 1;
    if (vg0 > NTOK-1) vg0 = NTOK-1;
    if (vg1 > NTOK-1) vg1 = NTOK-1;
    vr0 = *(const i32x4*)(Z + base + (size_t)vg0*HD + vd0);
    vr1 = *(const i32x4*)(Z + base + (size_t)vg1*HD + vd0);
  };
  auto STORE = [&](){
    char* kbp = (char*)Ks + skey*128;
    const int kx = (skey & 7) << 4;
    *(i32x4*)(kbp + ((sseg*32     ) ^ kx)) = kr0;
    *(i32x4*)(kbp + ((sseg*32 + 16) ^ kx)) = kr1;
    union { i32x4 v; ushort_t s[8]; } ua, ub;
    ua.v = vr0; ub.v = vr1;
    #pragma unroll
    for (int e = 0; e < 8; e++){
      const int ee = (e + g8) & 7;     // rotation: spreads banks across groups
      const int d  = vd0 + ee;         // d&7 == ee
      *(uint32_t*)((char*)Vt + d*128 + ((vk0*2) ^ (ee << 4))) =
          (uint32_t)ua.s[ee] | ((uint32_t)ub.s[ee] << 16);
    }
  };

  f32x4 acc[2][4] = {};     // [qt][dt4], rows=queries(4lq+r), cols=d(l16)
  float lsum[2] = {0.f, 0.f};

  LOADR(0);
  STORE();
  __syncthreads();

  for (int ch = 0; ch < NCHUNK; ch++){
    if (ch + 1 < NCHUNK) LOADR(ch + 1);   // in flight across the whole compute

    // S^T = K·Q^T fused with exp per 16-key tile (keeps s live-range at 8 regs)
    const bool lastch = (ch == NCHUNK-1);
    #pragma unroll
    for (int kt4 = 0; kt4 < 4; kt4++){
      f32x4 s0 = {}, s1 = {};
      #pragma unroll
      for (int ks = 0; ks < 2; ks++){
        hfrag kf = *(const hfrag*)((const char*)Ks + (kt4*16 + l16)*128
                                   + ((ks*64 + lq*16) ^ xk));
        s0 = __builtin_amdgcn_mfma_f32_16x16x32_f16(kf, qf[0][ks], s0, 0, 0, 0);
        s1 = __builtin_amdgcn_mfma_f32_16x16x32_f16(kf, qf[1][ks], s1, 0, 0, 0);
      }
      const int kb = kt4*16 + lq*4;
      #pragma unroll
      for (int qt = 0; qt < 2; qt++){
        const f32x4 sv = qt ? s1 : s0;
        float p0 = exp2_fast(sv[0] * temp);
        float p1 = exp2_fast(sv[1] * temp);
        float p2 = exp2_fast(sv[2] * temp);
        float p3 = exp2_fast(sv[3] * temp);
        if (lastch){
          if (kb + 0 >= LASTV) p0 = 0.f;
          if (kb + 1 >= LASTV) p1 = 0.f;
          if (kb + 2 >= LASTV) p2 = 0.f;
          if (kb + 3 >= LASTV) p3 = 0.f;
        }
        lsum[qt] += p0 + p1 + p2 + p3;
        union { _Float16 hh[4]; i32x2 v2; } pw;
        pw.hh[0] = (_Float16)p0; pw.hh[1] = (_Float16)p1;
        pw.hh[2] = (_Float16)p2; pw.hh[3] = (_Float16)p3;
        *(i32x2*)((char*)Pt + (w*32 + qt*16 + l16)*128
                  + ((kt4*32 + lq*8) ^ xk)) = pw.v2;
      }
    }

    // PV: acc[qt][dt4] += P(queries) @ V   (Pt rows are wave-private)
    #pragma unroll
    for (int ks = 0; ks < 2; ks++){
      const int cb = (ks*64 + lq*16) ^ xk;
      hfrag pa0 = *(const hfrag*)((const char*)Pt + (w*32 +      l16)*128 + cb);
      hfrag pa1 = *(const hfrag*)((const char*)Pt + (w*32 + 16 + l16)*128 + cb);
      #pragma unroll
      for (int dt4 = 0; dt4 < 4; dt4++){
        hfrag vf = *(const hfrag*)((const char*)Vt + (dt4*16 + l16)*128 + cb);
        acc[0][dt4] = __builtin_amdgcn_mfma_f32_16x16x32_f16(pa0, vf, acc[0][dt4], 0, 0, 0);
        acc[1][dt4] = __builtin_amdgcn_mfma_f32_16x16x32_f16(pa1, vf, acc[1][dt4], 0, 0, 0);
      }
    }
    __syncthreads();
    if (ch + 1 < NCHUNK){
      STORE();             // LDS write of prefetched chunk; loads already landed
      __syncthreads();
    }
  }

  // final row sums: reduce over lq groups, then redistribute to C-row owners
  float lfin[2];
  #pragma unroll
  for (int qt = 0; qt < 2; qt++){
    float lt = lsum[qt];
    lt += __shfl_xor(lt, 16);
    lt += __shfl_xor(lt, 32);
    lfin[qt] = lt;   // full sum for query qt*16+l16 (replicated across lq)
  }

  #pragma unroll
  for (int qt = 0; qt < 2; qt++)
    #pragma unroll
    for (int r = 0; r < 4; r++){
      const float lv = __int_as_float(
          __builtin_amdgcn_ds_bpermute((lq*4 + r) * 4, __float_as_int(lfin[qt])));
      const int n = row0 + w*32 + qt*16 + lq*4 + r;
      if (n < NTOK){
        const float inv = 1.0f / lv;
        const size_t rbase = (size_t)(n*BB + b) * CC + h*HD;
        if (mode == 0){
          ushort_t* yo = (ushort_t*)outp;
          #pragma unroll
          for (int dt4 = 0; dt4 < 4; dt4++){
            union { _Float16 h16; ushort_t u; } cv;
            cv.h16 = (_Float16)(acc[qt][dt4][r] * inv);
            yo[rbase + dt4*16 + l16] = cv.u;
          }
        } else {
          float* ao = (float*)outp;
          #pragma unroll
          for (int dt4 = 0; dt4 < 4; dt4++){
            float o = acc[qt][dt4][r] * inv;
            if (accum) o += ao[rbase + dt4*16 + l16];
            ao[rbase + dt4*16 + l16] = o;
          }
        }
      }
    }
}

// ---------------------------------------------------------------------------
extern "C" void kernel_launch(void* const* d_in, const int* in_sizes, int n_in,
                              void* d_out, int out_size, void* d_ws, size_t ws_size,
                              hipStream_t stream)
{
  (void)in_sizes; (void)n_in; (void)out_size; (void)ws_size;

  const float* x     = (const float*)d_in[0];   // fp32 [N,B,C]
  const float* wqkv  = (const float*)d_in[1];   // fp32 [2304,768]
  const float* wproj = (const float*)d_in[2];   // fp32 [768,768]
  const float* bias  = (const float*)d_in[3];   // fp32 [768]
  float* out = (float*)d_out;                   // fp32: [x_out | x_ori]

  ushort_t* x16  = (ushort_t*)d_ws;             // f16 [12552][768]
  ushort_t* wq16 = x16 + SZ;                    // f16 [2304][768]
  ushort_t* wp16 = wq16 + (size_t)2304*768;     // f16 [768][768]
  ushort_t* qb   = wp16 + (size_t)768*768;      // f16 [B,H,N,64] x3
  ushort_t* kb   = qb + SZ;
  ushort_t* vb   = kb + SZ;
  ushort_t* xh   = vb + SZ;                     // f16 [B,H,N,64] scratch
  ushort_t* y16  = xh + SZ;                     // f16 row-768 scratch (also acc16)
  float*    acc  = (float*)(y16 + SZ);          // fp32 row-768 accumulator
  float*    pre  = acc + SZ;                    // 8 floats

  hipMemsetAsync(pre, 0, BB * sizeof(float), stream);

  cvt_f16<<<(int)(SZ/8 + 255)/256, 256, 0, stream>>>(x, x16, (int)(SZ/8), 1.0f);
  cvt_f16<<<(2304*768/8 + 255)/256, 256, 0, stream>>>(wqkv, wq16, 2304*768/8, 1.0f);
  cvt_f16<<<(768*768/8 + 255)/256, 256, 0, stream>>>(wproj, wp16, 768*768/8, 1.0f);
  prenorm_kernel<<<dim3(50, 8), 256, 0, stream>>>(x, pre);

  gemm768<<<dim3(99, 18), 256, 0, stream>>>(x16, wq16, qb, kb, vb, nullptr, nullptr, 0);

  const float SCALE = 0.125f;                 // hd^-0.5
  const float FACT  = SCALE / (float)NTOK;    // inv_temp = pre[b] * FACT
  const dim3 AG(13, 96);

  // original attention -> x_ori (second output)
  attn_mfma<<<AG, 256, 0, stream>>>(qb, kb, vb, y16, nullptr, SCALE, 0, 0);
  gemm768<<<dim3(99, 6), 256, 0, stream>>>(y16, wp16, nullptr, nullptr, nullptr,
      out + (size_t)NTOK * BB * CC, bias, 1);

  // self-self branches over {q, k, v}
  const ushort_t* srcs[3] = { qb, kb, vb };
  for (int sI = 0; sI < 3; sI++){
    l2norm_kernel<<<NVEC/8, 256, 0, stream>>>(srcs[sI], xh, 0);
    attn_mfma<<<AG, 256, 0, stream>>>(xh, xh, xh, y16, pre, FACT, 0, 0);
    l2norm_kernel<<<NVEC/8, 256, 0, stream>>>(y16, xh, 1);
    attn_mfma<<<AG, 256, 0, stream>>>(xh, xh, vb, acc, pre, FACT, 1, sI == 0 ? 0 : 1);
  }

  // (sum/3) -> f16 (reuse y16) -> proj -> x_out (first output)
  cvt_f16<<<(int)(SZ/8 + 255)/256, 256, 0, stream>>>(acc, y16, (int)(SZ/8), 1.0f/3.0f);
  gemm768<<<dim3(99, 6), 256, 0, stream>>>(y16, wp16, nullptr, nullptr, nullptr,
      out, bias, 1);
}

// Round 6
// 1969.237 us; speedup vs baseline: 1.0483x; 1.0483x over previous
//
#include <hip/hip_runtime.h>
#include <stdint.h>

#define NTOK 1569
#define BB 8
#define CC 768
#define HH 12
#define HD 64
#define NBH (BB*HH)          // 96
#define NROW (NTOK*BB)       // 12552 rows of the [N*B][768] matrices
#define NCHUNK 25            // ceil(1569/64) key chunks
#define NVEC (NBH*NTOK)      // 150624 head-vectors
#define LASTV 33             // valid keys in last chunk: 1569 - 24*64

typedef unsigned short ushort_t;
static const size_t SZ = (size_t)NROW * CC;   // 9,639,936 elems (= NBH*NTOK*HD)

using f32x4 = __attribute__((ext_vector_type(4))) float;
using i32x4 = __attribute__((ext_vector_type(4))) int;
using i32x2 = __attribute__((ext_vector_type(2))) int;
using hfrag = __attribute__((ext_vector_type(8))) _Float16;

// v_exp_f32 computes 2^x; temp is pre-scaled by log2(e) so one trans op/elem.
__device__ __forceinline__ float exp2_fast(float x){
  float r;
  asm("v_exp_f32 %0, %1" : "=v"(r) : "v"(x));
  return r;
}

// ---------------------------------------------------------------------------
// pre[b] = sum_n ||x[n,b,:]||_2  (fp32 input)
// ---------------------------------------------------------------------------
__global__ __launch_bounds__(256) void prenorm_kernel(const float* __restrict__ x,
                                                      float* __restrict__ pre)
{
  const int b = blockIdx.y;
  const int wave = threadIdx.x >> 6, lane = threadIdx.x & 63;
  const int g = blockIdx.x * 4 + wave;          // [0, 200)
  float local = 0.f;
  for (int n = g; n < NTOK; n += 200){
    const float* xp = x + ((size_t)n * BB + b) * CC + lane * 4;
    float ss = 0.f;
    #pragma unroll
    for (int e = 0; e < 3; e++){
      f32x4 vv = *(const f32x4*)(xp + 256*e);
      ss += vv[0]*vv[0] + vv[1]*vv[1] + vv[2]*vv[2] + vv[3]*vv[3];
    }
    #pragma unroll
    for (int off = 1; off < 64; off <<= 1) ss += __shfl_xor(ss, off);
    local += sqrtf(ss);
  }
  if (lane == 0) atomicAdd(&pre[b], local);
}

// ---------------------------------------------------------------------------
// elementwise fp32 -> f16 (RTN), optional scale; n8 = elems/8
// ---------------------------------------------------------------------------
__global__ __launch_bounds__(256) void cvt_f16(const float* __restrict__ in,
                                               ushort_t* __restrict__ out,
                                               int n8, float scl)
{
  const int i = blockIdx.x * 256 + threadIdx.x;
  if (i >= n8) return;
  const float* p = in + (size_t)i * 8;
  f32x4 a = *(const f32x4*)p, b = *(const f32x4*)(p + 4);
  union { _Float16 h[8]; i32x4 v; } u;
  #pragma unroll
  for (int e = 0; e < 4; e++){
    u.h[e]   = (_Float16)(a[e] * scl);
    u.h[4+e] = (_Float16)(b[e] * scl);
  }
  *(i32x4*)(out + (size_t)i * 8) = u.v;
}

// ---------------------------------------------------------------------------
// f16 GEMM: C[m][j] = sum_c A[m][c] * B[j][c];  A [12552][768], B [Nj][768].
// 128x128 tile, BK=64, LDS layout [rowblk][kq][row16][8] (2-way max conflicts).
// mode 0: scatter f16 to q/k/v [B,H,N,64] (Nj=2304)
// mode 1: fp32 out[m*768 + j] + bias[j]       (Nj=768)
// grid: (99, Nj/128), block 256
// ---------------------------------------------------------------------------
__global__ __launch_bounds__(256) void gemm768(
    const ushort_t* __restrict__ A, const ushort_t* __restrict__ Bm,
    ushort_t* __restrict__ q, ushort_t* __restrict__ k, ushort_t* __restrict__ v,
    float* __restrict__ outp, const float* __restrict__ bias, int mode)
{
  __shared__ __align__(16) ushort_t As[8192];  // [rb 0..7][kq 0..7][r16 0..15][8]
  __shared__ __align__(16) ushort_t Bs[8192];

  const int mt = blockIdx.x, jt = blockIdx.y;
  const int tid = threadIdx.x;
  const int w = tid >> 6, lane = tid & 63;
  const int l16 = lane & 15, lq = lane >> 4;

  const int srow = tid & 127, shalf = tid >> 7;       // staging: row + col-half
  int ga = mt*128 + srow; if (ga > NROW-1) ga = NROW-1;
  const ushort_t* ap = A  + (size_t)ga * CC + shalf*32;
  const ushort_t* bp = Bm + (size_t)(jt*128 + srow) * CC + shalf*32;
  const int rb = srow >> 4, r16 = srow & 15;

  const int wr = (w >> 1) * 4, wc = (w & 1) * 4;      // 16-row/col block bases

  f32x4 acc[4][4] = {};
  for (int kt = 0; kt < 12; kt++){
    #pragma unroll
    for (int i = 0; i < 4; i++){
      const int kq = shalf*4 + i;
      *(i32x4*)&As[((rb*8 + kq)*16 + r16)*8] = *(const i32x4*)(ap + kt*64 + i*8);
      *(i32x4*)&Bs[((rb*8 + kq)*16 + r16)*8] = *(const i32x4*)(bp + kt*64 + i*8);
    }
    __syncthreads();
    #pragma unroll
    for (int ks = 0; ks < 2; ks++){
      hfrag af[4], bf[4];
      #pragma unroll
      for (int rt = 0; rt < 4; rt++)
        af[rt] = *(const hfrag*)&As[(((wr+rt)*8 + ks*4 + lq)*16 + l16)*8];
      #pragma unroll
      for (int ct = 0; ct < 4; ct++)
        bf[ct] = *(const hfrag*)&Bs[(((wc+ct)*8 + ks*4 + lq)*16 + l16)*8];
      #pragma unroll
      for (int rt = 0; rt < 4; rt++)
        #pragma unroll
        for (int ct = 0; ct < 4; ct++)
          acc[rt][ct] = __builtin_amdgcn_mfma_f32_16x16x32_f16(af[rt], bf[ct], acc[rt][ct], 0, 0, 0);
    }
    __syncthreads();
  }

  const int mbase = mt*128 + (w >> 1)*64;
  const int jbase = jt*128 + (w & 1)*64;
  #pragma unroll
  for (int ct = 0; ct < 4; ct++){
    const int j = jbase + ct*16 + l16;
    if (mode == 0){
      const int s = j / 768, jj = j - s*768;
      const int h = jj >> 6, d = jj & 63;
      ushort_t* op = (s == 0) ? q : (s == 1) ? k : v;
      #pragma unroll
      for (int rt = 0; rt < 4; rt++)
        #pragma unroll
        for (int r = 0; r < 4; r++){
          const int m = mbase + rt*16 + lq*4 + r;
          if (m < NROW){
            const int n = m >> 3, b = m & 7;
            union { _Float16 h16; ushort_t u; } cv;
            cv.h16 = (_Float16)acc[rt][ct][r];
            op[((size_t)(b*HH + h) * NTOK + n) * HD + d] = cv.u;
          }
        }
    } else {
      const float bv = bias[j];
      #pragma unroll
      for (int rt = 0; rt < 4; rt++)
        #pragma unroll
        for (int r = 0; r < 4; r++){
          const int m = mbase + rt*16 + lq*4 + r;
          if (m < NROW) outp[(size_t)m * CC + j] = acc[rt][ct][r] + bv;
        }
    }
  }
}

// ---------------------------------------------------------------------------
// l2 normalize per head-vector (64 elems), 32 lanes/vector, f16 in/out.
// mode 0: in is [B,H,N,64];  mode 1: in is row-768 layout [(n*8+b)][h*64+d]
// out: [B,H,N,64]
// ---------------------------------------------------------------------------
__global__ __launch_bounds__(256) void l2norm_kernel(const ushort_t* __restrict__ in,
                                                     ushort_t* __restrict__ out,
                                                     int mode)
{
  const int vec = blockIdx.x * 8 + (threadIdx.x >> 5);
  const int lane = threadIdx.x & 31;
  if (vec >= NVEC) return;
  size_t iaddr;
  if (mode == 0){
    iaddr = (size_t)vec * HD + lane*2;
  } else {
    const int b = vec / (HH*NTOK);
    const int rem = vec - b*(HH*NTOK);
    const int h = rem / NTOK, n = rem - h*NTOK;
    iaddr = (size_t)(n*BB + b) * CC + h*HD + lane*2;
  }
  union { ushort_t u[2]; uint32_t pk; _Float16 h[2]; } uv;
  uv.pk = *(const uint32_t*)(in + iaddr);
  const float a = (float)uv.h[0], c = (float)uv.h[1];
  float ss = a*a + c*c;
  #pragma unroll
  for (int off = 1; off < 32; off <<= 1) ss += __shfl_xor(ss, off);
  const float inv = 1.0f / fmaxf(sqrtf(ss), 1e-12f);
  union { _Float16 h[2]; uint32_t pk; } ov;
  ov.h[0] = (_Float16)(a * inv);
  ov.h[1] = (_Float16)(c * inv);
  *(uint32_t*)(out + (size_t)vec * HD + lane*2) = ov.pk;
}

// ---------------------------------------------------------------------------
// MFMA flash attention, transposed-S, max-free softmax (logits provably small).
// X,Y,Z f16 [B,H,N,64]. 128 queries/block (4 waves x 32), 64-key chunks.
//
// Kept from R1 (counter-validated):
//  * LDS stride-64 + XOR swizzle (byte ^= (row&7)<<4) for Ks/Vt/Pt -> 32 KiB,
//    conflict cycles 2.0e7 -> 6.0e6; Vt staging rotated by (tid>>3)&7.
//  * XCD-aware block remap (bijective 1248 = 8*156, 156 = 12 bh x 13 qblk):
//    all q-blocks of one (b,h) share an XCD L2 -> FETCH 178 -> ~45-60 MB.
//  * exp via single v_exp_f32 (temp pre-scaled by log2 e).
// Reverted from R1 (spill-inducing):
//  * NO register prefetch across compute, NO min-waves launch bound.
//    R1's __launch_bounds__(256,4) hard-capped VGPR+AGPR at 128/wave; the 16
//    persistent prefetch regs pushed past it -> scratch spills (WRITE_SIZE
//    38 -> 162 MB, latency serialized inside barriers, dur 154 -> 270 us).
// LDS: Ks 8K + Vt 8K + Pt 16K = 32 KiB.  grid: (13, 96)
// ---------------------------------------------------------------------------
__global__ __launch_bounds__(256) void attn_mfma(
    const ushort_t* __restrict__ X, const ushort_t* __restrict__ Y,
    const ushort_t* __restrict__ Z, void* __restrict__ outp,
    const float* __restrict__ pre, float tf, int mode, int accum)
{
  __shared__ __align__(16) ushort_t Ks[64*64];   // [key][d], swizzled
  __shared__ __align__(16) ushort_t Vt[64*64];   // [d][key], swizzled
  __shared__ __align__(16) ushort_t Pt[128*64];  // [q][key], swizzled

  // XCD-aware remap (bijective: 1248 = 8*156, 156 = 12*13)
  const int lin  = blockIdx.y * 13 + blockIdx.x;
  const int nl   = (lin & 7) * 156 + (lin >> 3);
  const int bh   = nl / 13;
  const int qblk = nl - bh * 13;

  const int b = bh / HH, h = bh - (bh / HH) * HH;
  const float temp = (pre ? pre[b] * tf : tf) * 1.4426950408889634f;
  const size_t base = (size_t)bh * NTOK * HD;
  const int row0 = qblk * 128;
  const int tid = threadIdx.x;
  const int w = tid >> 6, lane = tid & 63;
  const int l16 = lane & 15, lq = lane >> 4;
  const int xk = (l16 & 7) << 4;                 // swizzle key for compute reads

  // Q fragments (b-operand of S^T): rows row0 + w*32 + qt*16 + l16
  hfrag qf[2][2];
  #pragma unroll
  for (int qt = 0; qt < 2; qt++){
    int r = row0 + w*32 + qt*16 + l16; if (r > NTOK-1) r = NTOK-1;
    const ushort_t* qp = X + base + (size_t)r*HD + lq*8;
    qf[qt][0] = *(const hfrag*)qp;
    qf[qt][1] = *(const hfrag*)(qp + 32);
  }

  // staging maps
  const int skey = tid & 63, sseg = tid >> 6;              // K natural
  const int g8 = (tid >> 3) & 7;
  const int vd0 = g8 * 8;                                  // V^T: 8 d-rows
  const int vk0 = (tid & 7) * 2 + sseg * 16;               //      2 keys
  const int kx = (skey & 7) << 4;

  f32x4 acc[2][4] = {};     // [qt][dt4], rows=queries(4lq+r), cols=d(l16)
  float lsum[2] = {0.f, 0.f};

  for (int ch = 0; ch < NCHUNK; ch++){
    { // stage K (swizzled) and V (transposed + rotated + swizzled); short
      // register lifetimes: load->store back-to-back, compiler pipelines.
      int kg = ch*64 + skey; if (kg > NTOK-1) kg = NTOK-1;
      const ushort_t* kp = Y + base + (size_t)kg*HD + sseg*16;
      i32x4 kr0 = *(const i32x4*)kp;
      i32x4 kr1 = *(const i32x4*)(kp + 8);
      char* kbp = (char*)Ks + skey*128;
      *(i32x4*)(kbp + ((sseg*32     ) ^ kx)) = kr0;
      *(i32x4*)(kbp + ((sseg*32 + 16) ^ kx)) = kr1;

      int vg0 = ch*64 + vk0, vg1 = vg0 + 1;
      if (vg0 > NTOK-1) vg0 = NTOK-1;
      if (vg1 > NTOK-1) vg1 = NTOK-1;
      union { i32x4 v; ushort_t s[8]; } ua, ub;
      ua.v = *(const i32x4*)(Z + base + (size_t)vg0*HD + vd0);
      ub.v = *(const i32x4*)(Z + base + (size_t)vg1*HD + vd0);
      #pragma unroll
      for (int e = 0; e < 8; e++){
        const int ee = (e + g8) & 7;   // rotation: spreads banks across groups
        const int d  = vd0 + ee;       // d&7 == ee
        *(uint32_t*)((char*)Vt + d*128 + ((vk0*2) ^ (ee << 4))) =
            (uint32_t)ua.s[ee] | ((uint32_t)ub.s[ee] << 16);
      }
    }
    __syncthreads();

    // S^T = K·Q^T fused with exp per 16-key tile (keeps s live-range at 8 regs)
    const bool lastch = (ch == NCHUNK-1);
    #pragma unroll
    for (int kt4 = 0; kt4 < 4; kt4++){
      f32x4 s0 = {}, s1 = {};
      #pragma unroll
      for (int ks = 0; ks < 2; ks++){
        hfrag kf = *(const hfrag*)((const char*)Ks + (kt4*16 + l16)*128
                                   + ((ks*64 + lq*16) ^ xk));
        s0 = __builtin_amdgcn_mfma_f32_16x16x32_f16(kf, qf[0][ks], s0, 0, 0, 0);
        s1 = __builtin_amdgcn_mfma_f32_16x16x32_f16(kf, qf[1][ks], s1, 0, 0, 0);
      }
      const int kb = kt4*16 + lq*4;
      #pragma unroll
      for (int qt = 0; qt < 2; qt++){
        const f32x4 sv = qt ? s1 : s0;
        float p0 = exp2_fast(sv[0] * temp);
        float p1 = exp2_fast(sv[1] * temp);
        float p2 = exp2_fast(sv[2] * temp);
        float p3 = exp2_fast(sv[3] * temp);
        if (lastch){
          if (kb + 0 >= LASTV) p0 = 0.f;
          if (kb + 1 >= LASTV) p1 = 0.f;
          if (kb + 2 >= LASTV) p2 = 0.f;
          if (kb + 3 >= LASTV) p3 = 0.f;
        }
        lsum[qt] += p0 + p1 + p2 + p3;
        union { _Float16 hh[4]; i32x2 v2; } pw;
        pw.hh[0] = (_Float16)p0; pw.hh[1] = (_Float16)p1;
        pw.hh[2] = (_Float16)p2; pw.hh[3] = (_Float16)p3;
        *(i32x2*)((char*)Pt + (w*32 + qt*16 + l16)*128
                  + ((kt4*32 + lq*8) ^ xk)) = pw.v2;
      }
    }

    // PV: acc[qt][dt4] += P(queries) @ V   (Pt rows are wave-private)
    #pragma unroll
    for (int ks = 0; ks < 2; ks++){
      const int cb = (ks*64 + lq*16) ^ xk;
      hfrag pa0 = *(const hfrag*)((const char*)Pt + (w*32 +      l16)*128 + cb);
      hfrag pa1 = *(const hfrag*)((const char*)Pt + (w*32 + 16 + l16)*128 + cb);
      #pragma unroll
      for (int dt4 = 0; dt4 < 4; dt4++){
        hfrag vf = *(const hfrag*)((const char*)Vt + (dt4*16 + l16)*128 + cb);
        acc[0][dt4] = __builtin_amdgcn_mfma_f32_16x16x32_f16(pa0, vf, acc[0][dt4], 0, 0, 0);
        acc[1][dt4] = __builtin_amdgcn_mfma_f32_16x16x32_f16(pa1, vf, acc[1][dt4], 0, 0, 0);
      }
    }
    __syncthreads();
  }

  // final row sums: reduce over lq groups, then redistribute to C-row owners
  float lfin[2];
  #pragma unroll
  for (int qt = 0; qt < 2; qt++){
    float lt = lsum[qt];
    lt += __shfl_xor(lt, 16);
    lt += __shfl_xor(lt, 32);
    lfin[qt] = lt;   // full sum for query qt*16+l16 (replicated across lq)
  }

  #pragma unroll
  for (int qt = 0; qt < 2; qt++)
    #pragma unroll
    for (int r = 0; r < 4; r++){
      const float lv = __int_as_float(
          __builtin_amdgcn_ds_bpermute((lq*4 + r) * 4, __float_as_int(lfin[qt])));
      const int n = row0 + w*32 + qt*16 + lq*4 + r;
      if (n < NTOK){
        const float inv = 1.0f / lv;
        const size_t rbase = (size_t)(n*BB + b) * CC + h*HD;
        if (mode == 0){
          ushort_t* yo = (ushort_t*)outp;
          #pragma unroll
          for (int dt4 = 0; dt4 < 4; dt4++){
            union { _Float16 h16; ushort_t u; } cv;
            cv.h16 = (_Float16)(acc[qt][dt4][r] * inv);
            yo[rbase + dt4*16 + l16] = cv.u;
          }
        } else {
          float* ao = (float*)outp;
          #pragma unroll
          for (int dt4 = 0; dt4 < 4; dt4++){
            float o = acc[qt][dt4][r] * inv;
            if (accum) o += ao[rbase + dt4*16 + l16];
            ao[rbase + dt4*16 + l16] = o;
          }
        }
      }
    }
}

// ---------------------------------------------------------------------------
extern "C" void kernel_launch(void* const* d_in, const int* in_sizes, int n_in,
                              void* d_out, int out_size, void* d_ws, size_t ws_size,
                              hipStream_t stream)
{
  (void)in_sizes; (void)n_in; (void)out_size; (void)ws_size;

  const float* x     = (const float*)d_in[0];   // fp32 [N,B,C]
  const float* wqkv  = (const float*)d_in[1];   // fp32 [2304,768]
  const float* wproj = (const float*)d_in[2];   // fp32 [768,768]
  const float* bias  = (const float*)d_in[3];   // fp32 [768]
  float* out = (float*)d_out;                   // fp32: [x_out | x_ori]

  ushort_t* x16  = (ushort_t*)d_ws;             // f16 [12552][768]
  ushort_t* wq16 = x16 + SZ;                    // f16 [2304][768]
  ushort_t* wp16 = wq16 + (size_t)2304*768;     // f16 [768][768]
  ushort_t* qb   = wp16 + (size_t)768*768;      // f16 [B,H,N,64] x3
  ushort_t* kb   = qb + SZ;
  ushort_t* vb   = kb + SZ;
  ushort_t* xh   = vb + SZ;                     // f16 [B,H,N,64] scratch
  ushort_t* y16  = xh + SZ;                     // f16 row-768 scratch (also acc16)
  float*    acc  = (float*)(y16 + SZ);          // fp32 row-768 accumulator
  float*    pre  = acc + SZ;                    // 8 floats

  hipMemsetAsync(pre, 0, BB * sizeof(float), stream);

  cvt_f16<<<(int)(SZ/8 + 255)/256, 256, 0, stream>>>(x, x16, (int)(SZ/8), 1.0f);
  cvt_f16<<<(2304*768/8 + 255)/256, 256, 0, stream>>>(wqkv, wq16, 2304*768/8, 1.0f);
  cvt_f16<<<(768*768/8 + 255)/256, 256, 0, stream>>>(wproj, wp16, 768*768/8, 1.0f);
  prenorm_kernel<<<dim3(50, 8), 256, 0, stream>>>(x, pre);

  gemm768<<<dim3(99, 18), 256, 0, stream>>>(x16, wq16, qb, kb, vb, nullptr, nullptr, 0);

  const float SCALE = 0.125f;                 // hd^-0.5
  const float FACT  = SCALE / (float)NTOK;    // inv_temp = pre[b] * FACT
  const dim3 AG(13, 96);

  // original attention -> x_ori (second output)
  attn_mfma<<<AG, 256, 0, stream>>>(qb, kb, vb, y16, nullptr, SCALE, 0, 0);
  gemm768<<<dim3(99, 6), 256, 0, stream>>>(y16, wp16, nullptr, nullptr, nullptr,
      out + (size_t)NTOK * BB * CC, bias, 1);

  // self-self branches over {q, k, v}
  const ushort_t* srcs[3] = { qb, kb, vb };
  for (int sI = 0; sI < 3; sI++){
    l2norm_kernel<<<NVEC/8, 256, 0, stream>>>(srcs[sI], xh, 0);
    attn_mfma<<<AG, 256, 0, stream>>>(xh, xh, xh, y16, pre, FACT, 0, 0);
    l2norm_kernel<<<NVEC/8, 256, 0, stream>>>(y16, xh, 1);
    attn_mfma<<<AG, 256, 0, stream>>>(xh, xh, vb, acc, pre, FACT, 1, sI == 0 ? 0 : 1);
  }

  // (sum/3) -> f16 (reuse y16) -> proj -> x_out (first output)
  cvt_f16<<<(int)(SZ/8 + 255)/256, 256, 0, stream>>>(acc, y16, (int)(SZ/8), 1.0f/3.0f);
  gemm768<<<dim3(99, 6), 256, 0, stream>>>(y16, wp16, nullptr, nullptr, nullptr,
      out, bias, 1);
}

// Round 7
// 1246.954 us; speedup vs baseline: 1.6555x; 1.5792x over previous
//
#include <hip/hip_runtime.h>
#include <stdint.h>

#define NTOK 1569
#define BB 8
#define CC 768
#define HH 12
#define HD 64
#define NBH (BB*HH)          // 96
#define NROW (NTOK*BB)       // 12552 rows of the [N*B][768] matrices
#define NCHUNK 25            // ceil(1569/64) key chunks
#define NVEC (NBH*NTOK)      // 150624 head-vectors
#define LASTV 33             // valid keys in last chunk: 1569 - 24*64

typedef unsigned short ushort_t;
static const size_t SZ = (size_t)NROW * CC;   // 9,639,936 elems (= NBH*NTOK*HD)

using f32x4 = __attribute__((ext_vector_type(4))) float;
using i32x4 = __attribute__((ext_vector_type(4))) int;
using i32x2 = __attribute__((ext_vector_type(2))) int;
using hfrag = __attribute__((ext_vector_type(8))) _Float16;

// v_exp_f32 computes 2^x; temp is pre-scaled by log2(e) so one trans op/elem.
__device__ __forceinline__ float exp2_fast(float x){
  float r;
  asm("v_exp_f32 %0, %1" : "=v"(r) : "v"(x));
  return r;
}

// ---------------------------------------------------------------------------
// pre[b] = sum_n ||x[n,b,:]||_2  (fp32 input)
// ---------------------------------------------------------------------------
__global__ __launch_bounds__(256) void prenorm_kernel(const float* __restrict__ x,
                                                      float* __restrict__ pre)
{
  const int b = blockIdx.y;
  const int wave = threadIdx.x >> 6, lane = threadIdx.x & 63;
  const int g = blockIdx.x * 4 + wave;          // [0, 200)
  float local = 0.f;
  for (int n = g; n < NTOK; n += 200){
    const float* xp = x + ((size_t)n * BB + b) * CC + lane * 4;
    float ss = 0.f;
    #pragma unroll
    for (int e = 0; e < 3; e++){
      f32x4 vv = *(const f32x4*)(xp + 256*e);
      ss += vv[0]*vv[0] + vv[1]*vv[1] + vv[2]*vv[2] + vv[3]*vv[3];
    }
    #pragma unroll
    for (int off = 1; off < 64; off <<= 1) ss += __shfl_xor(ss, off);
    local += sqrtf(ss);
  }
  if (lane == 0) atomicAdd(&pre[b], local);
}

// ---------------------------------------------------------------------------
// elementwise fp32 -> f16 (RTN), optional scale; n8 = elems/8
// ---------------------------------------------------------------------------
__global__ __launch_bounds__(256) void cvt_f16(const float* __restrict__ in,
                                               ushort_t* __restrict__ out,
                                               int n8, float scl)
{
  const int i = blockIdx.x * 256 + threadIdx.x;
  if (i >= n8) return;
  const float* p = in + (size_t)i * 8;
  f32x4 a = *(const f32x4*)p, b = *(const f32x4*)(p + 4);
  union { _Float16 h[8]; i32x4 v; } u;
  #pragma unroll
  for (int e = 0; e < 4; e++){
    u.h[e]   = (_Float16)(a[e] * scl);
    u.h[4+e] = (_Float16)(b[e] * scl);
  }
  *(i32x4*)(out + (size_t)i * 8) = u.v;
}

// ---------------------------------------------------------------------------
// f16 GEMM: C[m][j] = sum_c A[m][c] * B[j][c];  A [12552][768], B [Nj][768].
// 128x128 tile, BK=64, LDS layout [rowblk][kq][row16][8] (2-way max conflicts).
// mode 0: scatter f16 to q/k/v [B,H,N,64] (Nj=2304)
// mode 1: fp32 out[m*768 + j] + bias[j]       (Nj=768)
// grid: (99, Nj/128), block 256
// ---------------------------------------------------------------------------
__global__ __launch_bounds__(256) void gemm768(
    const ushort_t* __restrict__ A, const ushort_t* __restrict__ Bm,
    ushort_t* __restrict__ q, ushort_t* __restrict__ k, ushort_t* __restrict__ v,
    float* __restrict__ outp, const float* __restrict__ bias, int mode)
{
  __shared__ __align__(16) ushort_t As[8192];  // [rb 0..7][kq 0..7][r16 0..15][8]
  __shared__ __align__(16) ushort_t Bs[8192];

  const int mt = blockIdx.x, jt = blockIdx.y;
  const int tid = threadIdx.x;
  const int w = tid >> 6, lane = tid & 63;
  const int l16 = lane & 15, lq = lane >> 4;

  const int srow = tid & 127, shalf = tid >> 7;       // staging: row + col-half
  int ga = mt*128 + srow; if (ga > NROW-1) ga = NROW-1;
  const ushort_t* ap = A  + (size_t)ga * CC + shalf*32;
  const ushort_t* bp = Bm + (size_t)(jt*128 + srow) * CC + shalf*32;
  const int rb = srow >> 4, r16 = srow & 15;

  const int wr = (w >> 1) * 4, wc = (w & 1) * 4;      // 16-row/col block bases

  f32x4 acc[4][4] = {};
  for (int kt = 0; kt < 12; kt++){
    #pragma unroll
    for (int i = 0; i < 4; i++){
      const int kq = shalf*4 + i;
      *(i32x4*)&As[((rb*8 + kq)*16 + r16)*8] = *(const i32x4*)(ap + kt*64 + i*8);
      *(i32x4*)&Bs[((rb*8 + kq)*16 + r16)*8] = *(const i32x4*)(bp + kt*64 + i*8);
    }
    __syncthreads();
    #pragma unroll
    for (int ks = 0; ks < 2; ks++){
      hfrag af[4], bf[4];
      #pragma unroll
      for (int rt = 0; rt < 4; rt++)
        af[rt] = *(const hfrag*)&As[(((wr+rt)*8 + ks*4 + lq)*16 + l16)*8];
      #pragma unroll
      for (int ct = 0; ct < 4; ct++)
        bf[ct] = *(const hfrag*)&Bs[(((wc+ct)*8 + ks*4 + lq)*16 + l16)*8];
      #pragma unroll
      for (int rt = 0; rt < 4; rt++)
        #pragma unroll
        for (int ct = 0; ct < 4; ct++)
          acc[rt][ct] = __builtin_amdgcn_mfma_f32_16x16x32_f16(af[rt], bf[ct], acc[rt][ct], 0, 0, 0);
    }
    __syncthreads();
  }

  const int mbase = mt*128 + (w >> 1)*64;
  const int jbase = jt*128 + (w & 1)*64;
  #pragma unroll
  for (int ct = 0; ct < 4; ct++){
    const int j = jbase + ct*16 + l16;
    if (mode == 0){
      const int s = j / 768, jj = j - s*768;
      const int h = jj >> 6, d = jj & 63;
      ushort_t* op = (s == 0) ? q : (s == 1) ? k : v;
      #pragma unroll
      for (int rt = 0; rt < 4; rt++)
        #pragma unroll
        for (int r = 0; r < 4; r++){
          const int m = mbase + rt*16 + lq*4 + r;
          if (m < NROW){
            const int n = m >> 3, b = m & 7;
            union { _Float16 h16; ushort_t u; } cv;
            cv.h16 = (_Float16)acc[rt][ct][r];
            op[((size_t)(b*HH + h) * NTOK + n) * HD + d] = cv.u;
          }
        }
    } else {
      const float bv = bias[j];
      #pragma unroll
      for (int rt = 0; rt < 4; rt++)
        #pragma unroll
        for (int r = 0; r < 4; r++){
          const int m = mbase + rt*16 + lq*4 + r;
          if (m < NROW) outp[(size_t)m * CC + j] = acc[rt][ct][r] + bv;
        }
    }
  }
}

// ---------------------------------------------------------------------------
// l2 normalize per head-vector (64 elems), 32 lanes/vector, f16 in/out.
// mode 0: in is [B,H,N,64];  mode 1: in is row-768 layout [(n*8+b)][h*64+d]
// out: [B,H,N,64]
// ---------------------------------------------------------------------------
__global__ __launch_bounds__(256) void l2norm_kernel(const ushort_t* __restrict__ in,
                                                     ushort_t* __restrict__ out,
                                                     int mode)
{
  const int vec = blockIdx.x * 8 + (threadIdx.x >> 5);
  const int lane = threadIdx.x & 31;
  if (vec >= NVEC) return;
  size_t iaddr;
  if (mode == 0){
    iaddr = (size_t)vec * HD + lane*2;
  } else {
    const int b = vec / (HH*NTOK);
    const int rem = vec - b*(HH*NTOK);
    const int h = rem / NTOK, n = rem - h*NTOK;
    iaddr = (size_t)(n*BB + b) * CC + h*HD + lane*2;
  }
  union { ushort_t u[2]; uint32_t pk; _Float16 h[2]; } uv;
  uv.pk = *(const uint32_t*)(in + iaddr);
  const float a = (float)uv.h[0], c = (float)uv.h[1];
  float ss = a*a + c*c;
  #pragma unroll
  for (int off = 1; off < 32; off <<= 1) ss += __shfl_xor(ss, off);
  const float inv = 1.0f / fmaxf(sqrtf(ss), 1e-12f);
  union { _Float16 h[2]; uint32_t pk; } ov;
  ov.h[0] = (_Float16)(a * inv);
  ov.h[1] = (_Float16)(c * inv);
  *(uint32_t*)(out + (size_t)vec * HD + lane*2) = ov.pk;
}

// ---------------------------------------------------------------------------
// MFMA flash attention, transposed-S, max-free softmax (logits provably small).
// X,Y,Z f16 [B,H,N,64]. 128 queries/block (4 waves x 32), 64-key chunks.
//
// R7 change (single variable vs R6): Vt staging rewritten with STATIC data
// indices. R6's rotation read ua.s[(e+g8)&7] — a runtime-indexed union ->
// scratch alloca (rule #20) -> 16 dependent scratch_load_ushort per chunk
// inside the barrier region. That latency chain was the ~93 us/dispatch stall
// (R6: MFMA busy-cycles == R0's, all pipes idle, dur 247 vs 154).
// New scheme: thread owns d-pair (d0=tid&31 -> rows 2d0,2d0+1) x key octet
// (ko=(tid>>5)*8). 8 coalesced dword loads (2 full key rows per instr),
// static shift/mask repack (fuses to v_perm_b32), 2 swizzled ds_write_b128
// (bank-balanced: 8 quad-starts x 8 lanes). Same logical LDS contract:
// Vt byte = d*128 + ((k*2) ^ ((d&7)<<4)); PV reads unchanged.
// Kept from R6: K/Pt XOR swizzle, XCD remap, exp2 direct.
// LDS: Ks 8K + Vt 8K + Pt 16K = 32 KiB.  grid: (13, 96)
// ---------------------------------------------------------------------------
__global__ __launch_bounds__(256) void attn_mfma(
    const ushort_t* __restrict__ X, const ushort_t* __restrict__ Y,
    const ushort_t* __restrict__ Z, void* __restrict__ outp,
    const float* __restrict__ pre, float tf, int mode, int accum)
{
  __shared__ __align__(16) ushort_t Ks[64*64];   // [key][d], swizzled
  __shared__ __align__(16) ushort_t Vt[64*64];   // [d][key], swizzled
  __shared__ __align__(16) ushort_t Pt[128*64];  // [q][key], swizzled

  // XCD-aware remap (bijective: 1248 = 8*156, 156 = 12*13)
  const int lin  = blockIdx.y * 13 + blockIdx.x;
  const int nl   = (lin & 7) * 156 + (lin >> 3);
  const int bh   = nl / 13;
  const int qblk = nl - bh * 13;

  const int b = bh / HH, h = bh - (bh / HH) * HH;
  const float temp = (pre ? pre[b] * tf : tf) * 1.4426950408889634f;
  const size_t base = (size_t)bh * NTOK * HD;
  const int row0 = qblk * 128;
  const int tid = threadIdx.x;
  const int w = tid >> 6, lane = tid & 63;
  const int l16 = lane & 15, lq = lane >> 4;
  const int xk = (l16 & 7) << 4;                 // swizzle key for compute reads

  // Q fragments (b-operand of S^T): rows row0 + w*32 + qt*16 + l16
  hfrag qf[2][2];
  #pragma unroll
  for (int qt = 0; qt < 2; qt++){
    int r = row0 + w*32 + qt*16 + l16; if (r > NTOK-1) r = NTOK-1;
    const ushort_t* qp = X + base + (size_t)r*HD + lq*8;
    qf[qt][0] = *(const hfrag*)qp;
    qf[qt][1] = *(const hfrag*)(qp + 32);
  }

  // staging maps
  const int skey = tid & 63, sseg = tid >> 6;              // K natural
  const int kx = (skey & 7) << 4;
  const int vd2 = (tid & 31) * 2;                          // V^T: row pair base
  const int vko = (tid >> 5) * 8;                          //      key octet

  f32x4 acc[2][4] = {};     // [qt][dt4], rows=queries(4lq+r), cols=d(l16)
  float lsum[2] = {0.f, 0.f};

  for (int ch = 0; ch < NCHUNK; ch++){
    { // stage K (swizzled); short register lifetimes
      int kg = ch*64 + skey; if (kg > NTOK-1) kg = NTOK-1;
      const ushort_t* kp = Y + base + (size_t)kg*HD + sseg*16;
      i32x4 kr0 = *(const i32x4*)kp;
      i32x4 kr1 = *(const i32x4*)(kp + 8);
      char* kbp = (char*)Ks + skey*128;
      *(i32x4*)(kbp + ((sseg*32     ) ^ kx)) = kr0;
      *(i32x4*)(kbp + ((sseg*32 + 16) ^ kx)) = kr1;

      // stage V^T: static repack (no runtime vector extract)
      uint32_t L[8];
      #pragma unroll
      for (int j = 0; j < 8; j++){
        int vg = ch*64 + vko + j; if (vg > NTOK-1) vg = NTOK-1;
        L[j] = *(const uint32_t*)(Z + base + (size_t)vg*HD + vd2);
      }
      i32x4 vlo, vhi;
      #pragma unroll
      for (int c = 0; c < 4; c++){
        const uint32_t A = L[2*c], B = L[2*c+1];
        vlo[c] = (int)((A & 0xffffu) | (B << 16));
        vhi[c] = (int)((A >> 16) | (B & 0xffff0000u));
      }
      char* vbp = (char*)Vt;
      *(i32x4*)(vbp + vd2*128     + ((vko*2) ^ ((vd2 & 7) << 4)))       = vlo;
      *(i32x4*)(vbp + (vd2+1)*128 + ((vko*2) ^ (((vd2+1) & 7) << 4)))   = vhi;
    }
    __syncthreads();

    // S^T = K·Q^T fused with exp per 16-key tile (keeps s live-range at 8 regs)
    const bool lastch = (ch == NCHUNK-1);
    #pragma unroll
    for (int kt4 = 0; kt4 < 4; kt4++){
      f32x4 s0 = {}, s1 = {};
      #pragma unroll
      for (int ks = 0; ks < 2; ks++){
        hfrag kf = *(const hfrag*)((const char*)Ks + (kt4*16 + l16)*128
                                   + ((ks*64 + lq*16) ^ xk));
        s0 = __builtin_amdgcn_mfma_f32_16x16x32_f16(kf, qf[0][ks], s0, 0, 0, 0);
        s1 = __builtin_amdgcn_mfma_f32_16x16x32_f16(kf, qf[1][ks], s1, 0, 0, 0);
      }
      const int kb = kt4*16 + lq*4;
      #pragma unroll
      for (int qt = 0; qt < 2; qt++){
        const f32x4 sv = qt ? s1 : s0;
        float p0 = exp2_fast(sv[0] * temp);
        float p1 = exp2_fast(sv[1] * temp);
        float p2 = exp2_fast(sv[2] * temp);
        float p3 = exp2_fast(sv[3] * temp);
        if (lastch){
          if (kb + 0 >= LASTV) p0 = 0.f;
          if (kb + 1 >= LASTV) p1 = 0.f;
          if (kb + 2 >= LASTV) p2 = 0.f;
          if (kb + 3 >= LASTV) p3 = 0.f;
        }
        lsum[qt] += p0 + p1 + p2 + p3;
        union { _Float16 hh[4]; i32x2 v2; } pw;
        pw.hh[0] = (_Float16)p0; pw.hh[1] = (_Float16)p1;
        pw.hh[2] = (_Float16)p2; pw.hh[3] = (_Float16)p3;
        *(i32x2*)((char*)Pt + (w*32 + qt*16 + l16)*128
                  + ((kt4*32 + lq*8) ^ xk)) = pw.v2;
      }
    }

    // PV: acc[qt][dt4] += P(queries) @ V   (Pt rows are wave-private)
    #pragma unroll
    for (int ks = 0; ks < 2; ks++){
      const int cb = (ks*64 + lq*16) ^ xk;
      hfrag pa0 = *(const hfrag*)((const char*)Pt + (w*32 +      l16)*128 + cb);
      hfrag pa1 = *(const hfrag*)((const char*)Pt + (w*32 + 16 + l16)*128 + cb);
      #pragma unroll
      for (int dt4 = 0; dt4 < 4; dt4++){
        hfrag vf = *(const hfrag*)((const char*)Vt + (dt4*16 + l16)*128 + cb);
        acc[0][dt4] = __builtin_amdgcn_mfma_f32_16x16x32_f16(pa0, vf, acc[0][dt4], 0, 0, 0);
        acc[1][dt4] = __builtin_amdgcn_mfma_f32_16x16x32_f16(pa1, vf, acc[1][dt4], 0, 0, 0);
      }
    }
    __syncthreads();
  }

  // final row sums: reduce over lq groups, then redistribute to C-row owners
  float lfin[2];
  #pragma unroll
  for (int qt = 0; qt < 2; qt++){
    float lt = lsum[qt];
    lt += __shfl_xor(lt, 16);
    lt += __shfl_xor(lt, 32);
    lfin[qt] = lt;   // full sum for query qt*16+l16 (replicated across lq)
  }

  #pragma unroll
  for (int qt = 0; qt < 2; qt++)
    #pragma unroll
    for (int r = 0; r < 4; r++){
      const float lv = __int_as_float(
          __builtin_amdgcn_ds_bpermute((lq*4 + r) * 4, __float_as_int(lfin[qt])));
      const int n = row0 + w*32 + qt*16 + lq*4 + r;
      if (n < NTOK){
        const float inv = 1.0f / lv;
        const size_t rbase = (size_t)(n*BB + b) * CC + h*HD;
        if (mode == 0){
          ushort_t* yo = (ushort_t*)outp;
          #pragma unroll
          for (int dt4 = 0; dt4 < 4; dt4++){
            union { _Float16 h16; ushort_t u; } cv;
            cv.h16 = (_Float16)(acc[qt][dt4][r] * inv);
            yo[rbase + dt4*16 + l16] = cv.u;
          }
        } else {
          float* ao = (float*)outp;
          #pragma unroll
          for (int dt4 = 0; dt4 < 4; dt4++){
            float o = acc[qt][dt4][r] * inv;
            if (accum) o += ao[rbase + dt4*16 + l16];
            ao[rbase + dt4*16 + l16] = o;
          }
        }
      }
    }
}

// ---------------------------------------------------------------------------
extern "C" void kernel_launch(void* const* d_in, const int* in_sizes, int n_in,
                              void* d_out, int out_size, void* d_ws, size_t ws_size,
                              hipStream_t stream)
{
  (void)in_sizes; (void)n_in; (void)out_size; (void)ws_size;

  const float* x     = (const float*)d_in[0];   // fp32 [N,B,C]
  const float* wqkv  = (const float*)d_in[1];   // fp32 [2304,768]
  const float* wproj = (const float*)d_in[2];   // fp32 [768,768]
  const float* bias  = (const float*)d_in[3];   // fp32 [768]
  float* out = (float*)d_out;                   // fp32: [x_out | x_ori]

  ushort_t* x16  = (ushort_t*)d_ws;             // f16 [12552][768]
  ushort_t* wq16 = x16 + SZ;                    // f16 [2304][768]
  ushort_t* wp16 = wq16 + (size_t)2304*768;     // f16 [768][768]
  ushort_t* qb   = wp16 + (size_t)768*768;      // f16 [B,H,N,64] x3
  ushort_t* kb   = qb + SZ;
  ushort_t* vb   = kb + SZ;
  ushort_t* xh   = vb + SZ;                     // f16 [B,H,N,64] scratch
  ushort_t* y16  = xh + SZ;                     // f16 row-768 scratch (also acc16)
  float*    acc  = (float*)(y16 + SZ);          // fp32 row-768 accumulator
  float*    pre  = acc + SZ;                    // 8 floats

  hipMemsetAsync(pre, 0, BB * sizeof(float), stream);

  cvt_f16<<<(int)(SZ/8 + 255)/256, 256, 0, stream>>>(x, x16, (int)(SZ/8), 1.0f);
  cvt_f16<<<(2304*768/8 + 255)/256, 256, 0, stream>>>(wqkv, wq16, 2304*768/8, 1.0f);
  cvt_f16<<<(768*768/8 + 255)/256, 256, 0, stream>>>(wproj, wp16, 768*768/8, 1.0f);
  prenorm_kernel<<<dim3(50, 8), 256, 0, stream>>>(x, pre);

  gemm768<<<dim3(99, 18), 256, 0, stream>>>(x16, wq16, qb, kb, vb, nullptr, nullptr, 0);

  const float SCALE = 0.125f;                 // hd^-0.5
  const float FACT  = SCALE / (float)NTOK;    // inv_temp = pre[b] * FACT
  const dim3 AG(13, 96);

  // original attention -> x_ori (second output)
  attn_mfma<<<AG, 256, 0, stream>>>(qb, kb, vb, y16, nullptr, SCALE, 0, 0);
  gemm768<<<dim3(99, 6), 256, 0, stream>>>(y16, wp16, nullptr, nullptr, nullptr,
      out + (size_t)NTOK * BB * CC, bias, 1);

  // self-self branches over {q, k, v}
  const ushort_t* srcs[3] = { qb, kb, vb };
  for (int sI = 0; sI < 3; sI++){
    l2norm_kernel<<<NVEC/8, 256, 0, stream>>>(srcs[sI], xh, 0);
    attn_mfma<<<AG, 256, 0, stream>>>(xh, xh, xh, y16, pre, FACT, 0, 0);
    l2norm_kernel<<<NVEC/8, 256, 0, stream>>>(y16, xh, 1);
    attn_mfma<<<AG, 256, 0, stream>>>(xh, xh, vb, acc, pre, FACT, 1, sI == 0 ? 0 : 1);
  }

  // (sum/3) -> f16 (reuse y16) -> proj -> x_out (first output)
  cvt_f16<<<(int)(SZ/8 + 255)/256, 256, 0, stream>>>(acc, y16, (int)(SZ/8), 1.0f/3.0f);
  gemm768<<<dim3(99, 6), 256, 0, stream>>>(y16, wp16, nullptr, nullptr, nullptr,
      out, bias, 1);
}

// Round 8
// 1192.304 us; speedup vs baseline: 1.7314x; 1.0458x over previous
//
#include <hip/hip_runtime.h>
#include <stdint.h>

#define NTOK 1569
#define BB 8
#define CC 768
#define HH 12
#define HD 64
#define NBH (BB*HH)          // 96
#define NROW (NTOK*BB)       // 12552 rows of the [N*B][768] matrices
#define NCHUNK 25            // ceil(1569/64) key chunks
#define NVEC (NBH*NTOK)      // 150624 head-vectors
#define LASTV 33             // valid keys in last chunk: 1569 - 24*64

typedef unsigned short ushort_t;
static const size_t SZ = (size_t)NROW * CC;   // 9,639,936 elems (= NBH*NTOK*HD)

using f32x4 = __attribute__((ext_vector_type(4))) float;
using i32x4 = __attribute__((ext_vector_type(4))) int;
using i32x2 = __attribute__((ext_vector_type(2))) int;
using hfrag = __attribute__((ext_vector_type(8))) _Float16;

// v_exp_f32 computes 2^x; temp is pre-scaled by log2(e) so one trans op/elem.
__device__ __forceinline__ float exp2_fast(float x){
  float r;
  asm("v_exp_f32 %0, %1" : "=v"(r) : "v"(x));
  return r;
}

// ---------------------------------------------------------------------------
// pre[b] = sum_n ||x[n,b,:]||_2  (fp32 input)
// ---------------------------------------------------------------------------
__global__ __launch_bounds__(256) void prenorm_kernel(const float* __restrict__ x,
                                                      float* __restrict__ pre)
{
  const int b = blockIdx.y;
  const int wave = threadIdx.x >> 6, lane = threadIdx.x & 63;
  const int g = blockIdx.x * 4 + wave;          // [0, 200)
  float local = 0.f;
  for (int n = g; n < NTOK; n += 200){
    const float* xp = x + ((size_t)n * BB + b) * CC + lane * 4;
    float ss = 0.f;
    #pragma unroll
    for (int e = 0; e < 3; e++){
      f32x4 vv = *(const f32x4*)(xp + 256*e);
      ss += vv[0]*vv[0] + vv[1]*vv[1] + vv[2]*vv[2] + vv[3]*vv[3];
    }
    #pragma unroll
    for (int off = 1; off < 64; off <<= 1) ss += __shfl_xor(ss, off);
    local += sqrtf(ss);
  }
  if (lane == 0) atomicAdd(&pre[b], local);
}

// ---------------------------------------------------------------------------
// elementwise fp32 -> f16 (RTN), optional scale; n8 = elems/8
// ---------------------------------------------------------------------------
__global__ __launch_bounds__(256) void cvt_f16(const float* __restrict__ in,
                                               ushort_t* __restrict__ out,
                                               int n8, float scl)
{
  const int i = blockIdx.x * 256 + threadIdx.x;
  if (i >= n8) return;
  const float* p = in + (size_t)i * 8;
  f32x4 a = *(const f32x4*)p, b = *(const f32x4*)(p + 4);
  union { _Float16 h[8]; i32x4 v; } u;
  #pragma unroll
  for (int e = 0; e < 4; e++){
    u.h[e]   = (_Float16)(a[e] * scl);
    u.h[4+e] = (_Float16)(b[e] * scl);
  }
  *(i32x4*)(out + (size_t)i * 8) = u.v;
}

// ---------------------------------------------------------------------------
// f16 GEMM: C[m][j] = sum_c A[m][c] * B[j][c];  A [12552][768], B [Nj][768].
// 128x128 tile, BK=64, LDS layout [rowblk][kq][row16][8] (2-way max conflicts).
// mode 0: scatter f16 to q/k/v [B,H,N,64] (Nj=2304)
// mode 1: fp32 out[m*768 + j] + bias[j]       (Nj=768)
// grid: (99, Nj/128), block 256
//
// R8: bijective XCD remap (1782 or 594 blocks -> 8 chunks, jt-fastest inside
// each chunk). HW round-robins lin%8 across XCDs; each XCD chunk then spans
// ~13 consecutive mt (A tiles, ~2.5 MB) x all jt (B cycling) -> concurrent
// working set fits the 4 MB XCD L2. R7 counters: FETCH 187 MB (A refetched
// ~10x of ideal 23 MB); predicted -> 40-60 MB.
// ---------------------------------------------------------------------------
__global__ __launch_bounds__(256) void gemm768(
    const ushort_t* __restrict__ A, const ushort_t* __restrict__ Bm,
    ushort_t* __restrict__ q, ushort_t* __restrict__ k, ushort_t* __restrict__ v,
    float* __restrict__ outp, const float* __restrict__ bias, int mode)
{
  __shared__ __align__(16) ushort_t As[8192];  // [rb 0..7][kq 0..7][r16 0..15][8]
  __shared__ __align__(16) ushort_t Bs[8192];

  // XCD-aware remap: lin -> (mt, jt), jt fastest within each XCD chunk
  const int jtN = gridDim.y;
  const int lin = blockIdx.y * 99 + blockIdx.x;
  const int T  = 99 * jtN;
  const int qq = T >> 3, rr = T & 7;
  const int c  = lin & 7, ii = lin >> 3;
  const int start = c*qq + (c < rr ? c : rr);
  const int idx = start + ii;
  const int mt = idx / jtN, jt = idx - mt*jtN;

  const int tid = threadIdx.x;
  const int w = tid >> 6, lane = tid & 63;
  const int l16 = lane & 15, lq = lane >> 4;

  const int srow = tid & 127, shalf = tid >> 7;       // staging: row + col-half
  int ga = mt*128 + srow; if (ga > NROW-1) ga = NROW-1;
  const ushort_t* ap = A  + (size_t)ga * CC + shalf*32;
  const ushort_t* bp = Bm + (size_t)(jt*128 + srow) * CC + shalf*32;
  const int rb = srow >> 4, r16 = srow & 15;

  const int wr = (w >> 1) * 4, wc = (w & 1) * 4;      // 16-row/col block bases

  f32x4 acc[4][4] = {};
  for (int kt = 0; kt < 12; kt++){
    #pragma unroll
    for (int i = 0; i < 4; i++){
      const int kq = shalf*4 + i;
      *(i32x4*)&As[((rb*8 + kq)*16 + r16)*8] = *(const i32x4*)(ap + kt*64 + i*8);
      *(i32x4*)&Bs[((rb*8 + kq)*16 + r16)*8] = *(const i32x4*)(bp + kt*64 + i*8);
    }
    __syncthreads();
    #pragma unroll
    for (int ks = 0; ks < 2; ks++){
      hfrag af[4], bf[4];
      #pragma unroll
      for (int rt = 0; rt < 4; rt++)
        af[rt] = *(const hfrag*)&As[(((wr+rt)*8 + ks*4 + lq)*16 + l16)*8];
      #pragma unroll
      for (int ct = 0; ct < 4; ct++)
        bf[ct] = *(const hfrag*)&Bs[(((wc+ct)*8 + ks*4 + lq)*16 + l16)*8];
      #pragma unroll
      for (int rt = 0; rt < 4; rt++)
        #pragma unroll
        for (int ct = 0; ct < 4; ct++)
          acc[rt][ct] = __builtin_amdgcn_mfma_f32_16x16x32_f16(af[rt], bf[ct], acc[rt][ct], 0, 0, 0);
    }
    __syncthreads();
  }

  const int mbase = mt*128 + (w >> 1)*64;
  const int jbase = jt*128 + (w & 1)*64;
  #pragma unroll
  for (int ct = 0; ct < 4; ct++){
    const int j = jbase + ct*16 + l16;
    if (mode == 0){
      const int s = j / 768, jj = j - s*768;
      const int h = jj >> 6, d = jj & 63;
      ushort_t* op = (s == 0) ? q : (s == 1) ? k : v;
      #pragma unroll
      for (int rt = 0; rt < 4; rt++)
        #pragma unroll
        for (int r = 0; r < 4; r++){
          const int m = mbase + rt*16 + lq*4 + r;
          if (m < NROW){
            const int n = m >> 3, b = m & 7;
            union { _Float16 h16; ushort_t u; } cv;
            cv.h16 = (_Float16)acc[rt][ct][r];
            op[((size_t)(b*HH + h) * NTOK + n) * HD + d] = cv.u;
          }
        }
    } else {
      const float bv = bias[j];
      #pragma unroll
      for (int rt = 0; rt < 4; rt++)
        #pragma unroll
        for (int r = 0; r < 4; r++){
          const int m = mbase + rt*16 + lq*4 + r;
          if (m < NROW) outp[(size_t)m * CC + j] = acc[rt][ct][r] + bv;
        }
    }
  }
}

// ---------------------------------------------------------------------------
// l2 normalize per head-vector (64 elems), 32 lanes/vector, f16 in/out.
// mode 0: in is [B,H,N,64];  mode 1: in is row-768 layout [(n*8+b)][h*64+d]
// out: [B,H,N,64]
// ---------------------------------------------------------------------------
__global__ __launch_bounds__(256) void l2norm_kernel(const ushort_t* __restrict__ in,
                                                     ushort_t* __restrict__ out,
                                                     int mode)
{
  const int vec = blockIdx.x * 8 + (threadIdx.x >> 5);
  const int lane = threadIdx.x & 31;
  if (vec >= NVEC) return;
  size_t iaddr;
  if (mode == 0){
    iaddr = (size_t)vec * HD + lane*2;
  } else {
    const int b = vec / (HH*NTOK);
    const int rem = vec - b*(HH*NTOK);
    const int h = rem / NTOK, n = rem - h*NTOK;
    iaddr = (size_t)(n*BB + b) * CC + h*HD + lane*2;
  }
  union { ushort_t u[2]; uint32_t pk; _Float16 h[2]; } uv;
  uv.pk = *(const uint32_t*)(in + iaddr);
  const float a = (float)uv.h[0], c = (float)uv.h[1];
  float ss = a*a + c*c;
  #pragma unroll
  for (int off = 1; off < 32; off <<= 1) ss += __shfl_xor(ss, off);
  const float inv = 1.0f / fmaxf(sqrtf(ss), 1e-12f);
  union { _Float16 h[2]; uint32_t pk; } ov;
  ov.h[0] = (_Float16)(a * inv);
  ov.h[1] = (_Float16)(c * inv);
  *(uint32_t*)(out + (size_t)vec * HD + lane*2) = ov.pk;
}

// ---------------------------------------------------------------------------
// MFMA flash attention, transposed-S, max-free softmax (logits provably small).
// X,Y,Z f16 [B,H,N,64]. 128 queries/block (4 waves x 32), 64-key chunks.
//
// R8 (single attn variable vs R7): T14 async-stage split. K/V of chunk ch+1
// are loaded into registers at the TOP of compute(ch) (global latency hides
// under ~450 cyc of MFMA+softmax), LDS-written after the barrier. This is
// R1's structure, now exonerated: R1's regression was the runtime-indexed
// union alloca (rule #20, fixed in R7) + the 128-reg launch bound (absent
// here). Prefetch holds 10 extra dwords; VGPR ~60 -> ~84, no launch bound.
// Kept: static-index V repack (R7), K/Pt XOR swizzle, XCD remap, exp2 direct.
// LDS: Ks 8K + Vt 8K + Pt 16K = 32 KiB.  grid: (13, 96)
// ---------------------------------------------------------------------------
__global__ __launch_bounds__(256) void attn_mfma(
    const ushort_t* __restrict__ X, const ushort_t* __restrict__ Y,
    const ushort_t* __restrict__ Z, void* __restrict__ outp,
    const float* __restrict__ pre, float tf, int mode, int accum)
{
  __shared__ __align__(16) ushort_t Ks[64*64];   // [key][d], swizzled
  __shared__ __align__(16) ushort_t Vt[64*64];   // [d][key], swizzled
  __shared__ __align__(16) ushort_t Pt[128*64];  // [q][key], swizzled

  // XCD-aware remap (bijective: 1248 = 8*156, 156 = 12*13)
  const int lin  = blockIdx.y * 13 + blockIdx.x;
  const int nl   = (lin & 7) * 156 + (lin >> 3);
  const int bh   = nl / 13;
  const int qblk = nl - bh * 13;

  const int b = bh / HH, h = bh - (bh / HH) * HH;
  const float temp = (pre ? pre[b] * tf : tf) * 1.4426950408889634f;
  const size_t base = (size_t)bh * NTOK * HD;
  const int row0 = qblk * 128;
  const int tid = threadIdx.x;
  const int w = tid >> 6, lane = tid & 63;
  const int l16 = lane & 15, lq = lane >> 4;
  const int xk = (l16 & 7) << 4;                 // swizzle key for compute reads

  // Q fragments (b-operand of S^T): rows row0 + w*32 + qt*16 + l16
  hfrag qf[2][2];
  #pragma unroll
  for (int qt = 0; qt < 2; qt++){
    int r = row0 + w*32 + qt*16 + l16; if (r > NTOK-1) r = NTOK-1;
    const ushort_t* qp = X + base + (size_t)r*HD + lq*8;
    qf[qt][0] = *(const hfrag*)qp;
    qf[qt][1] = *(const hfrag*)(qp + 32);
  }

  // staging maps
  const int skey = tid & 63, sseg = tid >> 6;              // K natural
  const int kx = (skey & 7) << 4;
  const int vd2 = (tid & 31) * 2;                          // V^T: row pair base
  const int vko = (tid >> 5) * 8;                          //      key octet

  // prefetch registers (static-indexed only; rule #20)
  i32x4 kr0, kr1;
  uint32_t L[8];

  auto LOADR = [&](int ch){
    int kg = ch*64 + skey; if (kg > NTOK-1) kg = NTOK-1;
    const ushort_t* kp = Y + base + (size_t)kg*HD + sseg*16;
    kr0 = *(const i32x4*)kp;
    kr1 = *(const i32x4*)(kp + 8);
    #pragma unroll
    for (int j = 0; j < 8; j++){
      int vg = ch*64 + vko + j; if (vg > NTOK-1) vg = NTOK-1;
      L[j] = *(const uint32_t*)(Z + base + (size_t)vg*HD + vd2);
    }
  };
  auto STORER = [&](){
    char* kbp = (char*)Ks + skey*128;
    *(i32x4*)(kbp + ((sseg*32     ) ^ kx)) = kr0;
    *(i32x4*)(kbp + ((sseg*32 + 16) ^ kx)) = kr1;
    i32x4 vlo, vhi;
    #pragma unroll
    for (int cc = 0; cc < 4; cc++){
      const uint32_t Aw = L[2*cc], Bw = L[2*cc+1];
      vlo[cc] = (int)((Aw & 0xffffu) | (Bw << 16));
      vhi[cc] = (int)((Aw >> 16) | (Bw & 0xffff0000u));
    }
    char* vbp = (char*)Vt;
    *(i32x4*)(vbp + vd2*128     + ((vko*2) ^ ((vd2 & 7) << 4)))     = vlo;
    *(i32x4*)(vbp + (vd2+1)*128 + ((vko*2) ^ (((vd2+1) & 7) << 4))) = vhi;
  };

  f32x4 acc[2][4] = {};     // [qt][dt4], rows=queries(4lq+r), cols=d(l16)
  float lsum[2] = {0.f, 0.f};

  LOADR(0);
  STORER();
  __syncthreads();

  for (int ch = 0; ch < NCHUNK; ch++){
    if (ch + 1 < NCHUNK) LOADR(ch + 1);   // in flight under the whole compute

    // S^T = K·Q^T fused with exp per 16-key tile (keeps s live-range at 8 regs)
    const bool lastch = (ch == NCHUNK-1);
    #pragma unroll
    for (int kt4 = 0; kt4 < 4; kt4++){
      f32x4 s0 = {}, s1 = {};
      #pragma unroll
      for (int ks = 0; ks < 2; ks++){
        hfrag kf = *(const hfrag*)((const char*)Ks + (kt4*16 + l16)*128
                                   + ((ks*64 + lq*16) ^ xk));
        s0 = __builtin_amdgcn_mfma_f32_16x16x32_f16(kf, qf[0][ks], s0, 0, 0, 0);
        s1 = __builtin_amdgcn_mfma_f32_16x16x32_f16(kf, qf[1][ks], s1, 0, 0, 0);
      }
      const int kb = kt4*16 + lq*4;
      #pragma unroll
      for (int qt = 0; qt < 2; qt++){
        const f32x4 sv = qt ? s1 : s0;
        float p0 = exp2_fast(sv[0] * temp);
        float p1 = exp2_fast(sv[1] * temp);
        float p2 = exp2_fast(sv[2] * temp);
        float p3 = exp2_fast(sv[3] * temp);
        if (lastch){
          if (kb + 0 >= LASTV) p0 = 0.f;
          if (kb + 1 >= LASTV) p1 = 0.f;
          if (kb + 2 >= LASTV) p2 = 0.f;
          if (kb + 3 >= LASTV) p3 = 0.f;
        }
        lsum[qt] += p0 + p1 + p2 + p3;
        union { _Float16 hh[4]; i32x2 v2; } pw;
        pw.hh[0] = (_Float16)p0; pw.hh[1] = (_Float16)p1;
        pw.hh[2] = (_Float16)p2; pw.hh[3] = (_Float16)p3;
        *(i32x2*)((char*)Pt + (w*32 + qt*16 + l16)*128
                  + ((kt4*32 + lq*8) ^ xk)) = pw.v2;
      }
    }

    // PV: acc[qt][dt4] += P(queries) @ V   (Pt rows are wave-private)
    #pragma unroll
    for (int ks = 0; ks < 2; ks++){
      const int cb = (ks*64 + lq*16) ^ xk;
      hfrag pa0 = *(const hfrag*)((const char*)Pt + (w*32 +      l16)*128 + cb);
      hfrag pa1 = *(const hfrag*)((const char*)Pt + (w*32 + 16 + l16)*128 + cb);
      #pragma unroll
      for (int dt4 = 0; dt4 < 4; dt4++){
        hfrag vf = *(const hfrag*)((const char*)Vt + (dt4*16 + l16)*128 + cb);
        acc[0][dt4] = __builtin_amdgcn_mfma_f32_16x16x32_f16(pa0, vf, acc[0][dt4], 0, 0, 0);
        acc[1][dt4] = __builtin_amdgcn_mfma_f32_16x16x32_f16(pa1, vf, acc[1][dt4], 0, 0, 0);
      }
    }
    __syncthreads();          // all reads of Ks/Vt(ch) complete
    if (ch + 1 < NCHUNK){
      STORER();               // loads have landed during compute; LDS write now
      __syncthreads();
    }
  }

  // final row sums: reduce over lq groups, then redistribute to C-row owners
  float lfin[2];
  #pragma unroll
  for (int qt = 0; qt < 2; qt++){
    float lt = lsum[qt];
    lt += __shfl_xor(lt, 16);
    lt += __shfl_xor(lt, 32);
    lfin[qt] = lt;   // full sum for query qt*16+l16 (replicated across lq)
  }

  #pragma unroll
  for (int qt = 0; qt < 2; qt++)
    #pragma unroll
    for (int r = 0; r < 4; r++){
      const float lv = __int_as_float(
          __builtin_amdgcn_ds_bpermute((lq*4 + r) * 4, __float_as_int(lfin[qt])));
      const int n = row0 + w*32 + qt*16 + lq*4 + r;
      if (n < NTOK){
        const float inv = 1.0f / lv;
        const size_t rbase = (size_t)(n*BB + b) * CC + h*HD;
        if (mode == 0){
          ushort_t* yo = (ushort_t*)outp;
          #pragma unroll
          for (int dt4 = 0; dt4 < 4; dt4++){
            union { _Float16 h16; ushort_t u; } cv;
            cv.h16 = (_Float16)(acc[qt][dt4][r] * inv);
            yo[rbase + dt4*16 + l16] = cv.u;
          }
        } else {
          float* ao = (float*)outp;
          #pragma unroll
          for (int dt4 = 0; dt4 < 4; dt4++){
            float o = acc[qt][dt4][r] * inv;
            if (accum) o += ao[rbase + dt4*16 + l16];
            ao[rbase + dt4*16 + l16] = o;
          }
        }
      }
    }
}

// ---------------------------------------------------------------------------
extern "C" void kernel_launch(void* const* d_in, const int* in_sizes, int n_in,
                              void* d_out, int out_size, void* d_ws, size_t ws_size,
                              hipStream_t stream)
{
  (void)in_sizes; (void)n_in; (void)out_size; (void)ws_size;

  const float* x     = (const float*)d_in[0];   // fp32 [N,B,C]
  const float* wqkv  = (const float*)d_in[1];   // fp32 [2304,768]
  const float* wproj = (const float*)d_in[2];   // fp32 [768,768]
  const float* bias  = (const float*)d_in[3];   // fp32 [768]
  float* out = (float*)d_out;                   // fp32: [x_out | x_ori]

  ushort_t* x16  = (ushort_t*)d_ws;             // f16 [12552][768]
  ushort_t* wq16 = x16 + SZ;                    // f16 [2304][768]
  ushort_t* wp16 = wq16 + (size_t)2304*768;     // f16 [768][768]
  ushort_t* qb   = wp16 + (size_t)768*768;      // f16 [B,H,N,64] x3
  ushort_t* kb   = qb + SZ;
  ushort_t* vb   = kb + SZ;
  ushort_t* xh   = vb + SZ;                     // f16 [B,H,N,64] scratch
  ushort_t* y16  = xh + SZ;                     // f16 row-768 scratch (also acc16)
  float*    acc  = (float*)(y16 + SZ);          // fp32 row-768 accumulator
  float*    pre  = acc + SZ;                    // 8 floats

  hipMemsetAsync(pre, 0, BB * sizeof(float), stream);

  cvt_f16<<<(int)(SZ/8 + 255)/256, 256, 0, stream>>>(x, x16, (int)(SZ/8), 1.0f);
  cvt_f16<<<(2304*768/8 + 255)/256, 256, 0, stream>>>(wqkv, wq16, 2304*768/8, 1.0f);
  cvt_f16<<<(768*768/8 + 255)/256, 256, 0, stream>>>(wproj, wp16, 768*768/8, 1.0f);
  prenorm_kernel<<<dim3(50, 8), 256, 0, stream>>>(x, pre);

  gemm768<<<dim3(99, 18), 256, 0, stream>>>(x16, wq16, qb, kb, vb, nullptr, nullptr, 0);

  const float SCALE = 0.125f;                 // hd^-0.5
  const float FACT  = SCALE / (float)NTOK;    // inv_temp = pre[b] * FACT
  const dim3 AG(13, 96);

  // original attention -> x_ori (second output)
  attn_mfma<<<AG, 256, 0, stream>>>(qb, kb, vb, y16, nullptr, SCALE, 0, 0);
  gemm768<<<dim3(99, 6), 256, 0, stream>>>(y16, wp16, nullptr, nullptr, nullptr,
      out + (size_t)NTOK * BB * CC, bias, 1);

  // self-self branches over {q, k, v}
  const ushort_t* srcs[3] = { qb, kb, vb };
  for (int sI = 0; sI < 3; sI++){
    l2norm_kernel<<<NVEC/8, 256, 0, stream>>>(srcs[sI], xh, 0);
    attn_mfma<<<AG, 256, 0, stream>>>(xh, xh, xh, y16, pre, FACT, 0, 0);
    l2norm_kernel<<<NVEC/8, 256, 0, stream>>>(y16, xh, 1);
    attn_mfma<<<AG, 256, 0, stream>>>(xh, xh, vb, acc, pre, FACT, 1, sI == 0 ? 0 : 1);
  }

  // (sum/3) -> f16 (reuse y16) -> proj -> x_out (first output)
  cvt_f16<<<(int)(SZ/8 + 255)/256, 256, 0, stream>>>(acc, y16, (int)(SZ/8), 1.0f/3.0f);
  gemm768<<<dim3(99, 6), 256, 0, stream>>>(y16, wp16, nullptr, nullptr, nullptr,
      out, bias, 1);
}

// Round 9
// 1156.997 us; speedup vs baseline: 1.7843x; 1.0305x over previous
//
#include <hip/hip_runtime.h>
#include <stdint.h>

#define NTOK 1569
#define BB 8
#define CC 768
#define HH 12
#define HD 64
#define NBH (BB*HH)          // 96
#define NROW (NTOK*BB)       // 12552 rows of the [N*B][768] matrices
#define NCHUNK 25            // ceil(1569/64) key chunks
#define NVEC (NBH*NTOK)      // 150624 head-vectors
#define LASTV 33             // valid keys in last chunk: 1569 - 24*64

typedef unsigned short ushort_t;
static const size_t SZ = (size_t)NROW * CC;   // 9,639,936 elems (= NBH*NTOK*HD)

using f32x4 = __attribute__((ext_vector_type(4))) float;
using i32x4 = __attribute__((ext_vector_type(4))) int;
using i32x2 = __attribute__((ext_vector_type(2))) int;
using hfrag = __attribute__((ext_vector_type(8))) _Float16;

// v_exp_f32 computes 2^x; temp is pre-scaled by log2(e) so one trans op/elem.
__device__ __forceinline__ float exp2_fast(float x){
  float r;
  asm("v_exp_f32 %0, %1" : "=v"(r) : "v"(x));
  return r;
}

// ---------------------------------------------------------------------------
// pre[b] = sum_n ||x[n,b,:]||_2  (fp32 input)
// ---------------------------------------------------------------------------
__global__ __launch_bounds__(256) void prenorm_kernel(const float* __restrict__ x,
                                                      float* __restrict__ pre)
{
  const int b = blockIdx.y;
  const int wave = threadIdx.x >> 6, lane = threadIdx.x & 63;
  const int g = blockIdx.x * 4 + wave;          // [0, 200)
  float local = 0.f;
  for (int n = g; n < NTOK; n += 200){
    const float* xp = x + ((size_t)n * BB + b) * CC + lane * 4;
    float ss = 0.f;
    #pragma unroll
    for (int e = 0; e < 3; e++){
      f32x4 vv = *(const f32x4*)(xp + 256*e);
      ss += vv[0]*vv[0] + vv[1]*vv[1] + vv[2]*vv[2] + vv[3]*vv[3];
    }
    #pragma unroll
    for (int off = 1; off < 64; off <<= 1) ss += __shfl_xor(ss, off);
    local += sqrtf(ss);
  }
  if (lane == 0) atomicAdd(&pre[b], local);
}

// ---------------------------------------------------------------------------
// elementwise fp32 -> f16 (RTN), optional scale; n8 = elems/8
// ---------------------------------------------------------------------------
__global__ __launch_bounds__(256) void cvt_f16(const float* __restrict__ in,
                                               ushort_t* __restrict__ out,
                                               int n8, float scl)
{
  const int i = blockIdx.x * 256 + threadIdx.x;
  if (i >= n8) return;
  const float* p = in + (size_t)i * 8;
  f32x4 a = *(const f32x4*)p, b = *(const f32x4*)(p + 4);
  union { _Float16 h[8]; i32x4 v; } u;
  #pragma unroll
  for (int e = 0; e < 4; e++){
    u.h[e]   = (_Float16)(a[e] * scl);
    u.h[4+e] = (_Float16)(b[e] * scl);
  }
  *(i32x4*)(out + (size_t)i * 8) = u.v;
}

// ---------------------------------------------------------------------------
// f16 GEMM: C[m][j] = sum_c A[m][c] * B[j][c];  A [12552][768], B [Nj][768].
// 128x128 tile, BK=64, LDS layout [rowblk][kq][row16][8] (2-way max conflicts).
// mode 0: scatter f16 to q/k/v [B,H,N,64] (Nj=2304)
// mode 1: fp32 out[m*768 + j] + bias[j]       (Nj=768)
// grid: (99, Nj/128), block 256
// R8 (validated): bijective XCD remap, jt-fastest per XCD chunk -> A-tile
// reuse inside the 4 MB XCD L2 (gemm768 QKV dropped out of top-5).
// ---------------------------------------------------------------------------
__global__ __launch_bounds__(256) void gemm768(
    const ushort_t* __restrict__ A, const ushort_t* __restrict__ Bm,
    ushort_t* __restrict__ q, ushort_t* __restrict__ k, ushort_t* __restrict__ v,
    float* __restrict__ outp, const float* __restrict__ bias, int mode)
{
  __shared__ __align__(16) ushort_t As[8192];  // [rb 0..7][kq 0..7][r16 0..15][8]
  __shared__ __align__(16) ushort_t Bs[8192];

  // XCD-aware remap: lin -> (mt, jt), jt fastest within each XCD chunk
  const int jtN = gridDim.y;
  const int lin = blockIdx.y * 99 + blockIdx.x;
  const int T  = 99 * jtN;
  const int qq = T >> 3, rr = T & 7;
  const int c  = lin & 7, ii = lin >> 3;
  const int start = c*qq + (c < rr ? c : rr);
  const int idx = start + ii;
  const int mt = idx / jtN, jt = idx - mt*jtN;

  const int tid = threadIdx.x;
  const int w = tid >> 6, lane = tid & 63;
  const int l16 = lane & 15, lq = lane >> 4;

  const int srow = tid & 127, shalf = tid >> 7;       // staging: row + col-half
  int ga = mt*128 + srow; if (ga > NROW-1) ga = NROW-1;
  const ushort_t* ap = A  + (size_t)ga * CC + shalf*32;
  const ushort_t* bp = Bm + (size_t)(jt*128 + srow) * CC + shalf*32;
  const int rb = srow >> 4, r16 = srow & 15;

  const int wr = (w >> 1) * 4, wc = (w & 1) * 4;      // 16-row/col block bases

  f32x4 acc[4][4] = {};
  for (int kt = 0; kt < 12; kt++){
    #pragma unroll
    for (int i = 0; i < 4; i++){
      const int kq = shalf*4 + i;
      *(i32x4*)&As[((rb*8 + kq)*16 + r16)*8] = *(const i32x4*)(ap + kt*64 + i*8);
      *(i32x4*)&Bs[((rb*8 + kq)*16 + r16)*8] = *(const i32x4*)(bp + kt*64 + i*8);
    }
    __syncthreads();
    #pragma unroll
    for (int ks = 0; ks < 2; ks++){
      hfrag af[4], bf[4];
      #pragma unroll
      for (int rt = 0; rt < 4; rt++)
        af[rt] = *(const hfrag*)&As[(((wr+rt)*8 + ks*4 + lq)*16 + l16)*8];
      #pragma unroll
      for (int ct = 0; ct < 4; ct++)
        bf[ct] = *(const hfrag*)&Bs[(((wc+ct)*8 + ks*4 + lq)*16 + l16)*8];
      #pragma unroll
      for (int rt = 0; rt < 4; rt++)
        #pragma unroll
        for (int ct = 0; ct < 4; ct++)
          acc[rt][ct] = __builtin_amdgcn_mfma_f32_16x16x32_f16(af[rt], bf[ct], acc[rt][ct], 0, 0, 0);
    }
    __syncthreads();
  }

  const int mbase = mt*128 + (w >> 1)*64;
  const int jbase = jt*128 + (w & 1)*64;
  #pragma unroll
  for (int ct = 0; ct < 4; ct++){
    const int j = jbase + ct*16 + l16;
    if (mode == 0){
      const int s = j / 768, jj = j - s*768;
      const int h = jj >> 6, d = jj & 63;
      ushort_t* op = (s == 0) ? q : (s == 1) ? k : v;
      #pragma unroll
      for (int rt = 0; rt < 4; rt++)
        #pragma unroll
        for (int r = 0; r < 4; r++){
          const int m = mbase + rt*16 + lq*4 + r;
          if (m < NROW){
            const int n = m >> 3, b = m & 7;
            union { _Float16 h16; ushort_t u; } cv;
            cv.h16 = (_Float16)acc[rt][ct][r];
            op[((size_t)(b*HH + h) * NTOK + n) * HD + d] = cv.u;
          }
        }
    } else {
      const float bv = bias[j];
      #pragma unroll
      for (int rt = 0; rt < 4; rt++)
        #pragma unroll
        for (int r = 0; r < 4; r++){
          const int m = mbase + rt*16 + lq*4 + r;
          if (m < NROW) outp[(size_t)m * CC + j] = acc[rt][ct][r] + bv;
        }
    }
  }
}

// ---------------------------------------------------------------------------
// l2 normalize per head-vector (64 elems), 32 lanes/vector, f16 in/out.
// mode 0: in is [B,H,N,64];  mode 1: in is row-768 layout [(n*8+b)][h*64+d]
// out: [B,H,N,64]
// ---------------------------------------------------------------------------
__global__ __launch_bounds__(256) void l2norm_kernel(const ushort_t* __restrict__ in,
                                                     ushort_t* __restrict__ out,
                                                     int mode)
{
  const int vec = blockIdx.x * 8 + (threadIdx.x >> 5);
  const int lane = threadIdx.x & 31;
  if (vec >= NVEC) return;
  size_t iaddr;
  if (mode == 0){
    iaddr = (size_t)vec * HD + lane*2;
  } else {
    const int b = vec / (HH*NTOK);
    const int rem = vec - b*(HH*NTOK);
    const int h = rem / NTOK, n = rem - h*NTOK;
    iaddr = (size_t)(n*BB + b) * CC + h*HD + lane*2;
  }
  union { ushort_t u[2]; uint32_t pk; _Float16 h[2]; } uv;
  uv.pk = *(const uint32_t*)(in + iaddr);
  const float a = (float)uv.h[0], c = (float)uv.h[1];
  float ss = a*a + c*c;
  #pragma unroll
  for (int off = 1; off < 32; off <<= 1) ss += __shfl_xor(ss, off);
  const float inv = 1.0f / fmaxf(sqrtf(ss), 1e-12f);
  union { _Float16 h[2]; uint32_t pk; } ov;
  ov.h[0] = (_Float16)(a * inv);
  ov.h[1] = (_Float16)(c * inv);
  *(uint32_t*)(out + (size_t)vec * HD + lane*2) = ov.pk;
}

// ---------------------------------------------------------------------------
// MFMA flash attention, transposed-S, max-free softmax (logits provably small).
// X,Y,Z f16 [B,H,N,64]. 128 queries/block (4 waves x 32), 64-key chunks.
//
// R9 changes (both in this kernel; attn was 76% of runtime, VALUBusy 46%):
//  1. Row-sums via MFMA: P fragments x all-ones B-operand (4 extra MFMA/chunk)
//     accumulate sum_k P[q][k] into acc1[qt] whose C-layout row (lq*4+r)
//     matches the epilogue's query index exactly. Deletes 32 serial VALU
//     adds/chunk + the epilogue shuffle/bpermute redistribution.
//  2. K/V LDS double-buffer -> ONE barrier per chunk. STORER((ch+1)&1) runs
//     BEFORE the barrier: that buffer was last read in chunk ch-1, and the
//     end-of-(ch-1) barrier ordered those reads before any chunk-ch write.
// Kept: T14 reg prefetch (R8), static-index V repack (R7), XOR swizzle (R1),
// XCD remap (R1), exp2 direct (R1). No launch bound (R1 lesson).
// LDS: Ks 2x8K + Vt 2x8K + Pt 16K = 48 KiB.  grid: (13, 96)
// ---------------------------------------------------------------------------
__global__ __launch_bounds__(256) void attn_mfma(
    const ushort_t* __restrict__ X, const ushort_t* __restrict__ Y,
    const ushort_t* __restrict__ Z, void* __restrict__ outp,
    const float* __restrict__ pre, float tf, int mode, int accum)
{
  __shared__ __align__(16) ushort_t Ks[2][64*64];   // [key][d], swizzled
  __shared__ __align__(16) ushort_t Vt[2][64*64];   // [d][key], swizzled
  __shared__ __align__(16) ushort_t Pt[128*64];     // [q][key], swizzled

  // XCD-aware remap (bijective: 1248 = 8*156, 156 = 12*13)
  const int lin  = blockIdx.y * 13 + blockIdx.x;
  const int nl   = (lin & 7) * 156 + (lin >> 3);
  const int bh   = nl / 13;
  const int qblk = nl - bh * 13;

  const int b = bh / HH, h = bh - (bh / HH) * HH;
  const float temp = (pre ? pre[b] * tf : tf) * 1.4426950408889634f;
  const size_t base = (size_t)bh * NTOK * HD;
  const int row0 = qblk * 128;
  const int tid = threadIdx.x;
  const int w = tid >> 6, lane = tid & 63;
  const int l16 = lane & 15, lq = lane >> 4;
  const int xk = (l16 & 7) << 4;                 // swizzle key for compute reads

  // Q fragments (b-operand of S^T): rows row0 + w*32 + qt*16 + l16
  hfrag qf[2][2];
  #pragma unroll
  for (int qt = 0; qt < 2; qt++){
    int r = row0 + w*32 + qt*16 + l16; if (r > NTOK-1) r = NTOK-1;
    const ushort_t* qp = X + base + (size_t)r*HD + lq*8;
    qf[qt][0] = *(const hfrag*)qp;
    qf[qt][1] = *(const hfrag*)(qp + 32);
  }

  hfrag ones;
  #pragma unroll
  for (int e = 0; e < 8; e++) ones[e] = (_Float16)1.0f;

  // staging maps
  const int skey = tid & 63, sseg = tid >> 6;              // K natural
  const int kx = (skey & 7) << 4;
  const int vd2 = (tid & 31) * 2;                          // V^T: row pair base
  const int vko = (tid >> 5) * 8;                          //      key octet

  // prefetch registers (static-indexed only; rule #20)
  i32x4 kr0, kr1;
  uint32_t L[8];

  auto LOADR = [&](int ch){
    int kg = ch*64 + skey; if (kg > NTOK-1) kg = NTOK-1;
    const ushort_t* kp = Y + base + (size_t)kg*HD + sseg*16;
    kr0 = *(const i32x4*)kp;
    kr1 = *(const i32x4*)(kp + 8);
    #pragma unroll
    for (int j = 0; j < 8; j++){
      int vg = ch*64 + vko + j; if (vg > NTOK-1) vg = NTOK-1;
      L[j] = *(const uint32_t*)(Z + base + (size_t)vg*HD + vd2);
    }
  };
  auto STORER = [&](int bf){
    char* kbp = (char*)Ks[bf] + skey*128;
    *(i32x4*)(kbp + ((sseg*32     ) ^ kx)) = kr0;
    *(i32x4*)(kbp + ((sseg*32 + 16) ^ kx)) = kr1;
    i32x4 vlo, vhi;
    #pragma unroll
    for (int cc = 0; cc < 4; cc++){
      const uint32_t Aw = L[2*cc], Bw = L[2*cc+1];
      vlo[cc] = (int)((Aw & 0xffffu) | (Bw << 16));
      vhi[cc] = (int)((Aw >> 16) | (Bw & 0xffff0000u));
    }
    char* vbp = (char*)Vt[bf];
    *(i32x4*)(vbp + vd2*128     + ((vko*2) ^ ((vd2 & 7) << 4)))     = vlo;
    *(i32x4*)(vbp + (vd2+1)*128 + ((vko*2) ^ (((vd2+1) & 7) << 4))) = vhi;
  };

  f32x4 acc[2][4] = {};     // [qt][dt4], rows=queries(4lq+r), cols=d(l16)
  f32x4 acc1[2] = {};       // row sums: sum_k P, same row mapping, any col

  LOADR(0);
  STORER(0);
  __syncthreads();

  for (int ch = 0; ch < NCHUNK; ch++){
    const int cur = ch & 1;
    const char* Kc = (const char*)Ks[cur];
    const char* Vc = (const char*)Vt[cur];
    if (ch + 1 < NCHUNK) LOADR(ch + 1);   // in flight under the whole compute

    // S^T = K·Q^T fused with exp per 16-key tile (keeps s live-range at 8 regs)
    const bool lastch = (ch == NCHUNK-1);
    #pragma unroll
    for (int kt4 = 0; kt4 < 4; kt4++){
      f32x4 s0 = {}, s1 = {};
      #pragma unroll
      for (int ks = 0; ks < 2; ks++){
        hfrag kf = *(const hfrag*)(Kc + (kt4*16 + l16)*128
                                   + ((ks*64 + lq*16) ^ xk));
        s0 = __builtin_amdgcn_mfma_f32_16x16x32_f16(kf, qf[0][ks], s0, 0, 0, 0);
        s1 = __builtin_amdgcn_mfma_f32_16x16x32_f16(kf, qf[1][ks], s1, 0, 0, 0);
      }
      const int kb = kt4*16 + lq*4;
      #pragma unroll
      for (int qt = 0; qt < 2; qt++){
        const f32x4 sv = qt ? s1 : s0;
        float p0 = exp2_fast(sv[0] * temp);
        float p1 = exp2_fast(sv[1] * temp);
        float p2 = exp2_fast(sv[2] * temp);
        float p3 = exp2_fast(sv[3] * temp);
        if (lastch){
          if (kb + 0 >= LASTV) p0 = 0.f;
          if (kb + 1 >= LASTV) p1 = 0.f;
          if (kb + 2 >= LASTV) p2 = 0.f;
          if (kb + 3 >= LASTV) p3 = 0.f;
        }
        union { _Float16 hh[4]; i32x2 v2; } pw;
        pw.hh[0] = (_Float16)p0; pw.hh[1] = (_Float16)p1;
        pw.hh[2] = (_Float16)p2; pw.hh[3] = (_Float16)p3;
        *(i32x2*)((char*)Pt + (w*32 + qt*16 + l16)*128
                  + ((kt4*32 + lq*8) ^ xk)) = pw.v2;
      }
    }

    // PV: acc[qt][dt4] += P(queries) @ V; acc1[qt] += P @ ones (row sums)
    #pragma unroll
    for (int ks = 0; ks < 2; ks++){
      const int cb = (ks*64 + lq*16) ^ xk;
      hfrag pa0 = *(const hfrag*)((const char*)Pt + (w*32 +      l16)*128 + cb);
      hfrag pa1 = *(const hfrag*)((const char*)Pt + (w*32 + 16 + l16)*128 + cb);
      #pragma unroll
      for (int dt4 = 0; dt4 < 4; dt4++){
        hfrag vf = *(const hfrag*)(Vc + (dt4*16 + l16)*128 + cb);
        acc[0][dt4] = __builtin_amdgcn_mfma_f32_16x16x32_f16(pa0, vf, acc[0][dt4], 0, 0, 0);
        acc[1][dt4] = __builtin_amdgcn_mfma_f32_16x16x32_f16(pa1, vf, acc[1][dt4], 0, 0, 0);
      }
      acc1[0] = __builtin_amdgcn_mfma_f32_16x16x32_f16(pa0, ones, acc1[0], 0, 0, 0);
      acc1[1] = __builtin_amdgcn_mfma_f32_16x16x32_f16(pa1, ones, acc1[1], 0, 0, 0);
    }

    if (ch + 1 < NCHUNK){
      STORER(cur ^ 1);      // buf cur^1 last read in ch-1; barrier ordered it
      __syncthreads();      // writes visible; reads of cur done before reuse
    }
  }

  // epilogue: acc1[qt][r] already holds the full row sum in the owner lane
  #pragma unroll
  for (int qt = 0; qt < 2; qt++)
    #pragma unroll
    for (int r = 0; r < 4; r++){
      const int n = row0 + w*32 + qt*16 + lq*4 + r;
      if (n < NTOK){
        const float inv = 1.0f / acc1[qt][r];
        const size_t rbase = (size_t)(n*BB + b) * CC + h*HD;
        if (mode == 0){
          ushort_t* yo = (ushort_t*)outp;
          #pragma unroll
          for (int dt4 = 0; dt4 < 4; dt4++){
            union { _Float16 h16; ushort_t u; } cv;
            cv.h16 = (_Float16)(acc[qt][dt4][r] * inv);
            yo[rbase + dt4*16 + l16] = cv.u;
          }
        } else {
          float* ao = (float*)outp;
          #pragma unroll
          for (int dt4 = 0; dt4 < 4; dt4++){
            float o = acc[qt][dt4][r] * inv;
            if (accum) o += ao[rbase + dt4*16 + l16];
            ao[rbase + dt4*16 + l16] = o;
          }
        }
      }
    }
}

// ---------------------------------------------------------------------------
extern "C" void kernel_launch(void* const* d_in, const int* in_sizes, int n_in,
                              void* d_out, int out_size, void* d_ws, size_t ws_size,
                              hipStream_t stream)
{
  (void)in_sizes; (void)n_in; (void)out_size; (void)ws_size;

  const float* x     = (const float*)d_in[0];   // fp32 [N,B,C]
  const float* wqkv  = (const float*)d_in[1];   // fp32 [2304,768]
  const float* wproj = (const float*)d_in[2];   // fp32 [768,768]
  const float* bias  = (const float*)d_in[3];   // fp32 [768]
  float* out = (float*)d_out;                   // fp32: [x_out | x_ori]

  ushort_t* x16  = (ushort_t*)d_ws;             // f16 [12552][768]
  ushort_t* wq16 = x16 + SZ;                    // f16 [2304][768]
  ushort_t* wp16 = wq16 + (size_t)2304*768;     // f16 [768][768]
  ushort_t* qb   = wp16 + (size_t)768*768;      // f16 [B,H,N,64] x3
  ushort_t* kb   = qb + SZ;
  ushort_t* vb   = kb + SZ;
  ushort_t* xh   = vb + SZ;                     // f16 [B,H,N,64] scratch
  ushort_t* y16  = xh + SZ;                     // f16 row-768 scratch (also acc16)
  float*    acc  = (float*)(y16 + SZ);          // fp32 row-768 accumulator
  float*    pre  = acc + SZ;                    // 8 floats

  hipMemsetAsync(pre, 0, BB * sizeof(float), stream);

  cvt_f16<<<(int)(SZ/8 + 255)/256, 256, 0, stream>>>(x, x16, (int)(SZ/8), 1.0f);
  cvt_f16<<<(2304*768/8 + 255)/256, 256, 0, stream>>>(wqkv, wq16, 2304*768/8, 1.0f);
  cvt_f16<<<(768*768/8 + 255)/256, 256, 0, stream>>>(wproj, wp16, 768*768/8, 1.0f);
  prenorm_kernel<<<dim3(50, 8), 256, 0, stream>>>(x, pre);

  gemm768<<<dim3(99, 18), 256, 0, stream>>>(x16, wq16, qb, kb, vb, nullptr, nullptr, 0);

  const float SCALE = 0.125f;                 // hd^-0.5
  const float FACT  = SCALE / (float)NTOK;    // inv_temp = pre[b] * FACT
  const dim3 AG(13, 96);

  // original attention -> x_ori (second output)
  attn_mfma<<<AG, 256, 0, stream>>>(qb, kb, vb, y16, nullptr, SCALE, 0, 0);
  gemm768<<<dim3(99, 6), 256, 0, stream>>>(y16, wp16, nullptr, nullptr, nullptr,
      out + (size_t)NTOK * BB * CC, bias, 1);

  // self-self branches over {q, k, v}
  const ushort_t* srcs[3] = { qb, kb, vb };
  for (int sI = 0; sI < 3; sI++){
    l2norm_kernel<<<NVEC/8, 256, 0, stream>>>(srcs[sI], xh, 0);
    attn_mfma<<<AG, 256, 0, stream>>>(xh, xh, xh, y16, pre, FACT, 0, 0);
    l2norm_kernel<<<NVEC/8, 256, 0, stream>>>(y16, xh, 1);
    attn_mfma<<<AG, 256, 0, stream>>>(xh, xh, vb, acc, pre, FACT, 1, sI == 0 ? 0 : 1);
  }

  // (sum/3) -> f16 (reuse y16) -> proj -> x_out (first output)
  cvt_f16<<<(int)(SZ/8 + 255)/256, 256, 0, stream>>>(acc, y16, (int)(SZ/8), 1.0f/3.0f);
  gemm768<<<dim3(99, 6), 256, 0, stream>>>(y16, wp16, nullptr, nullptr, nullptr,
      out, bias, 1);
}

// Round 11
// 1088.892 us; speedup vs baseline: 1.8959x; 1.0625x over previous
//
#include <hip/hip_runtime.h>
#include <stdint.h>

#define NTOK 1569
#define BB 8
#define CC 768
#define HH 12
#define HD 64
#define NBH (BB*HH)          // 96
#define NROW (NTOK*BB)       // 12552 rows of the [N*B][768] matrices
#define NCHUNK 25            // ceil(1569/64) key chunks
#define NVEC (NBH*NTOK)      // 150624 head-vectors
#define LASTV 33             // valid keys in last chunk: 1569 - 24*64

typedef unsigned short ushort_t;
static const size_t SZ = (size_t)NROW * CC;   // 9,639,936 elems (= NBH*NTOK*HD)

using f32x4 = __attribute__((ext_vector_type(4))) float;
using i32x4 = __attribute__((ext_vector_type(4))) int;
using i32x2 = __attribute__((ext_vector_type(2))) int;
using hfrag = __attribute__((ext_vector_type(8))) _Float16;

// v_exp_f32 computes 2^x; temp is pre-scaled by log2(e) so one trans op/elem.
__device__ __forceinline__ float exp2_fast(float x){
  float r;
  asm("v_exp_f32 %0, %1" : "=v"(r) : "v"(x));
  return r;
}

// ---------------------------------------------------------------------------
// pre[b] = sum_n ||x[n,b,:]||_2  (fp32 input)
// ---------------------------------------------------------------------------
__global__ __launch_bounds__(256) void prenorm_kernel(const float* __restrict__ x,
                                                      float* __restrict__ pre)
{
  const int b = blockIdx.y;
  const int wave = threadIdx.x >> 6, lane = threadIdx.x & 63;
  const int g = blockIdx.x * 4 + wave;          // [0, 200)
  float local = 0.f;
  for (int n = g; n < NTOK; n += 200){
    const float* xp = x + ((size_t)n * BB + b) * CC + lane * 4;
    float ss = 0.f;
    #pragma unroll
    for (int e = 0; e < 3; e++){
      f32x4 vv = *(const f32x4*)(xp + 256*e);
      ss += vv[0]*vv[0] + vv[1]*vv[1] + vv[2]*vv[2] + vv[3]*vv[3];
    }
    #pragma unroll
    for (int off = 1; off < 64; off <<= 1) ss += __shfl_xor(ss, off);
    local += sqrtf(ss);
  }
  if (lane == 0) atomicAdd(&pre[b], local);
}

// ---------------------------------------------------------------------------
// elementwise fp32 -> f16 (RTN), optional scale; n8 = elems/8
// ---------------------------------------------------------------------------
__global__ __launch_bounds__(256) void cvt_f16(const float* __restrict__ in,
                                               ushort_t* __restrict__ out,
                                               int n8, float scl)
{
  const int i = blockIdx.x * 256 + threadIdx.x;
  if (i >= n8) return;
  const float* p = in + (size_t)i * 8;
  f32x4 a = *(const f32x4*)p, b = *(const f32x4*)(p + 4);
  union { _Float16 h[8]; i32x4 v; } u;
  #pragma unroll
  for (int e = 0; e < 4; e++){
    u.h[e]   = (_Float16)(a[e] * scl);
    u.h[4+e] = (_Float16)(b[e] * scl);
  }
  *(i32x4*)(out + (size_t)i * 8) = u.v;
}

// ---------------------------------------------------------------------------
// f16 GEMM: C[m][j] = sum_c A[m][c] * B[j][c];  A [12552][768], B [Nj][768].
// 128x128 tile, BK=64. R10: staging via global_load_lds width=16 (m97
// structure). LDS is LINEAR in chunk index j = row*8 + cb (16B chunks); wave
// w issue i fills chunks i*256+w*64+lane (1KB contiguous per instruction —
// HW requirement). The column swizzle moved to the SOURCE (rule #21): lane
// reads col-block kq = (lane&7) ^ (lane>>3), so LDS slot cb holds colblk
// cb ^ (row&7); compute reads XOR the same -> lanes spread over all 8 bank
// slots (minimal LDS cycles). Each 8-lane group still covers one contiguous
// 128B row segment -> global coalescing preserved.
// mode 0: scatter f16 to q/k/v [B,H,N,64] (Nj=2304)
// mode 1: fp32 out[m*768 + j] + bias[j]       (Nj=768)
// grid: (99, Nj/128), block 256.  XCD remap (R8, validated).
// ---------------------------------------------------------------------------
__global__ __launch_bounds__(256) void gemm768(
    const ushort_t* __restrict__ A, const ushort_t* __restrict__ Bm,
    ushort_t* __restrict__ q, ushort_t* __restrict__ k, ushort_t* __restrict__ v,
    float* __restrict__ outp, const float* __restrict__ bias, int mode)
{
  __shared__ __align__(16) ushort_t As[8192];  // [row 0..127][cb 0..7][8], cb swizzled
  __shared__ __align__(16) ushort_t Bs[8192];

  // XCD-aware remap: lin -> (mt, jt), jt fastest within each XCD chunk
  const int jtN = gridDim.y;
  const int lin = blockIdx.y * 99 + blockIdx.x;
  const int T  = 99 * jtN;
  const int qq = T >> 3, rr = T & 7;
  const int c  = lin & 7, ii = lin >> 3;
  const int start = c*qq + (c < rr ? c : rr);
  const int idx = start + ii;
  const int mt = idx / jtN, jt = idx - mt*jtN;

  const int tid = threadIdx.x;
  const int w = tid >> 6, lane = tid & 63;
  const int l16 = lane & 15, lq = lane >> 4;

  // staging source map: lane -> (row-quad, swizzled colblk)
  const int rquad = lane >> 3;                 // 0..7
  const int kqs   = (lane & 7) ^ rquad;        // source colblk (inverse swz)
  const ushort_t* apb[4];
  const ushort_t* bpb[4];
  #pragma unroll
  for (int i = 0; i < 4; i++){
    int ar = mt*128 + i*32 + w*8 + rquad; if (ar > NROW-1) ar = NROW-1;
    apb[i] = A + (size_t)ar*CC + kqs*8;
    const int br = jt*128 + i*32 + w*8 + rquad;
    bpb[i] = Bm + (size_t)br*CC + kqs*8;
  }

  const int wr = (w >> 1) * 4, wc = (w & 1) * 4;      // 16-row/col block bases
  const int rx = l16 & 7;                             // read-side swizzle key

  f32x4 acc[4][4] = {};
  for (int kt = 0; kt < 12; kt++){
    #pragma unroll
    for (int i = 0; i < 4; i++){
      __builtin_amdgcn_global_load_lds(
          (const __attribute__((address_space(1))) void*)apb[i],
          (__attribute__((address_space(3))) void*)&As[(i*256 + w*64)*8],
          16, 0, 0);
      __builtin_amdgcn_global_load_lds(
          (const __attribute__((address_space(1))) void*)bpb[i],
          (__attribute__((address_space(3))) void*)&Bs[(i*256 + w*64)*8],
          16, 0, 0);
      apb[i] += 64; bpb[i] += 64;
    }
    __syncthreads();   // compiler drains vmcnt before barrier (m97 structure)
    #pragma unroll
    for (int ks = 0; ks < 2; ks++){
      hfrag af[4], bf[4];
      #pragma unroll
      for (int rt = 0; rt < 4; rt++)
        af[rt] = *(const hfrag*)((const char*)As
                   + ((wr+rt)*16 + l16)*128 + ((((ks*4+lq) ^ rx)) << 4));
      #pragma unroll
      for (int ct = 0; ct < 4; ct++)
        bf[ct] = *(const hfrag*)((const char*)Bs
                   + ((wc+ct)*16 + l16)*128 + ((((ks*4+lq) ^ rx)) << 4));
      #pragma unroll
      for (int rt = 0; rt < 4; rt++)
        #pragma unroll
        for (int ct = 0; ct < 4; ct++)
          acc[rt][ct] = __builtin_amdgcn_mfma_f32_16x16x32_f16(af[rt], bf[ct], acc[rt][ct], 0, 0, 0);
    }
    __syncthreads();
  }

  const int mbase = mt*128 + (w >> 1)*64;
  const int jbase = jt*128 + (w & 1)*64;
  #pragma unroll
  for (int ct = 0; ct < 4; ct++){
    const int j = jbase + ct*16 + l16;
    if (mode == 0){
      const int s = j / 768, jj = j - s*768;
      const int h = jj >> 6, d = jj & 63;
      ushort_t* op = (s == 0) ? q : (s == 1) ? k : v;
      #pragma unroll
      for (int rt = 0; rt < 4; rt++)
        #pragma unroll
        for (int r = 0; r < 4; r++){
          const int m = mbase + rt*16 + lq*4 + r;
          if (m < NROW){
            const int n = m >> 3, b = m & 7;
            union { _Float16 h16; ushort_t u; } cv;
            cv.h16 = (_Float16)acc[rt][ct][r];
            op[((size_t)(b*HH + h) * NTOK + n) * HD + d] = cv.u;
          }
        }
    } else {
      const float bv = bias[j];
      #pragma unroll
      for (int rt = 0; rt < 4; rt++)
        #pragma unroll
        for (int r = 0; r < 4; r++){
          const int m = mbase + rt*16 + lq*4 + r;
          if (m < NROW) outp[(size_t)m * CC + j] = acc[rt][ct][r] + bv;
        }
    }
  }
}

// ---------------------------------------------------------------------------
// l2 normalize per head-vector (64 elems), 32 lanes/vector, f16 in/out.
// mode 0: in is [B,H,N,64];  mode 1: in is row-768 layout [(n*8+b)][h*64+d]
// out: [B,H,N,64]
// ---------------------------------------------------------------------------
__global__ __launch_bounds__(256) void l2norm_kernel(const ushort_t* __restrict__ in,
                                                     ushort_t* __restrict__ out,
                                                     int mode)
{
  const int vec = blockIdx.x * 8 + (threadIdx.x >> 5);
  const int lane = threadIdx.x & 31;
  if (vec >= NVEC) return;
  size_t iaddr;
  if (mode == 0){
    iaddr = (size_t)vec * HD + lane*2;
  } else {
    const int b = vec / (HH*NTOK);
    const int rem = vec - b*(HH*NTOK);
    const int h = rem / NTOK, n = rem - h*NTOK;
    iaddr = (size_t)(n*BB + b) * CC + h*HD + lane*2;
  }
  union { ushort_t u[2]; uint32_t pk; _Float16 h[2]; } uv;
  uv.pk = *(const uint32_t*)(in + iaddr);
  const float a = (float)uv.h[0], c = (float)uv.h[1];
  float ss = a*a + c*c;
  #pragma unroll
  for (int off = 1; off < 32; off <<= 1) ss += __shfl_xor(ss, off);
  const float inv = 1.0f / fmaxf(sqrtf(ss), 1e-12f);
  union { _Float16 h[2]; uint32_t pk; } ov;
  ov.h[0] = (_Float16)(a * inv);
  ov.h[1] = (_Float16)(c * inv);
  *(uint32_t*)(out + (size_t)vec * HD + lane*2) = ov.pk;
}

// ---------------------------------------------------------------------------
// MFMA flash attention, transposed-S, max-free softmax (logits provably small).
// X,Y,Z f16 [B,H,N,64]. 128 queries/block (4 waves x 32), 64-key chunks.
//
// R9 (validated): MFMA row-sums (P x ones -> acc1, epilogue lane mapping
// matches), K/V LDS double-buffer with ONE barrier per chunk.
// R10: mode 2 epilogue — reads fp32 accumulator accin, adds own contribution,
// scales by 1/3, writes f16 to outp (row-768). Replaces the final cvt_f16
// pass (58 MB of traffic + a launch).
// Kept: T14 reg prefetch (R8), static-index V repack (R7), XOR swizzle,
// XCD remap, exp2 direct. No launch bound (R1 lesson).
// LDS: Ks 2x8K + Vt 2x8K + Pt 16K = 48 KiB.  grid: (13, 96)
// ---------------------------------------------------------------------------
__global__ __launch_bounds__(256) void attn_mfma(
    const ushort_t* __restrict__ X, const ushort_t* __restrict__ Y,
    const ushort_t* __restrict__ Z, void* __restrict__ outp,
    const float* __restrict__ accin,
    const float* __restrict__ pre, float tf, int mode, int accum)
{
  __shared__ __align__(16) ushort_t Ks[2][64*64];   // [key][d], swizzled
  __shared__ __align__(16) ushort_t Vt[2][64*64];   // [d][key], swizzled
  __shared__ __align__(16) ushort_t Pt[128*64];     // [q][key], swizzled

  // XCD-aware remap (bijective: 1248 = 8*156, 156 = 12*13)
  const int lin  = blockIdx.y * 13 + blockIdx.x;
  const int nl   = (lin & 7) * 156 + (lin >> 3);
  const int bh   = nl / 13;
  const int qblk = nl - bh * 13;

  const int b = bh / HH, h = bh - (bh / HH) * HH;
  const float temp = (pre ? pre[b] * tf : tf) * 1.4426950408889634f;
  const size_t base = (size_t)bh * NTOK * HD;
  const int row0 = qblk * 128;
  const int tid = threadIdx.x;
  const int w = tid >> 6, lane = tid & 63;
  const int l16 = lane & 15, lq = lane >> 4;
  const int xk = (l16 & 7) << 4;                 // swizzle key for compute reads

  // Q fragments (b-operand of S^T): rows row0 + w*32 + qt*16 + l16
  hfrag qf[2][2];
  #pragma unroll
  for (int qt = 0; qt < 2; qt++){
    int r = row0 + w*32 + qt*16 + l16; if (r > NTOK-1) r = NTOK-1;
    const ushort_t* qp = X + base + (size_t)r*HD + lq*8;
    qf[qt][0] = *(const hfrag*)qp;
    qf[qt][1] = *(const hfrag*)(qp + 32);
  }

  hfrag ones;
  #pragma unroll
  for (int e = 0; e < 8; e++) ones[e] = (_Float16)1.0f;

  // staging maps
  const int skey = tid & 63, sseg = tid >> 6;              // K natural
  const int kx = (skey & 7) << 4;
  const int vd2 = (tid & 31) * 2;                          // V^T: row pair base
  const int vko = (tid >> 5) * 8;                          //      key octet

  // prefetch registers (static-indexed only; rule #20)
  i32x4 kr0, kr1;
  uint32_t L[8];

  auto LOADR = [&](int ch){
    int kg = ch*64 + skey; if (kg > NTOK-1) kg = NTOK-1;
    const ushort_t* kp = Y + base + (size_t)kg*HD + sseg*16;
    kr0 = *(const i32x4*)kp;
    kr1 = *(const i32x4*)(kp + 8);
    #pragma unroll
    for (int j = 0; j < 8; j++){
      int vg = ch*64 + vko + j; if (vg > NTOK-1) vg = NTOK-1;
      L[j] = *(const uint32_t*)(Z + base + (size_t)vg*HD + vd2);
    }
  };
  auto STORER = [&](int bf){
    char* kbp = (char*)Ks[bf] + skey*128;
    *(i32x4*)(kbp + ((sseg*32     ) ^ kx)) = kr0;
    *(i32x4*)(kbp + ((sseg*32 + 16) ^ kx)) = kr1;
    i32x4 vlo, vhi;
    #pragma unroll
    for (int cc = 0; cc < 4; cc++){
      const uint32_t Aw = L[2*cc], Bw = L[2*cc+1];
      vlo[cc] = (int)((Aw & 0xffffu) | (Bw << 16));
      vhi[cc] = (int)((Aw >> 16) | (Bw & 0xffff0000u));
    }
    char* vbp = (char*)Vt[bf];
    *(i32x4*)(vbp + vd2*128     + ((vko*2) ^ ((vd2 & 7) << 4)))     = vlo;
    *(i32x4*)(vbp + (vd2+1)*128 + ((vko*2) ^ (((vd2+1) & 7) << 4))) = vhi;
  };

  f32x4 acc[2][4] = {};     // [qt][dt4], rows=queries(4lq+r), cols=d(l16)
  f32x4 acc1[2] = {};       // row sums: sum_k P, same row mapping, any col

  LOADR(0);
  STORER(0);
  __syncthreads();

  for (int ch = 0; ch < NCHUNK; ch++){
    const int cur = ch & 1;
    const char* Kc = (const char*)Ks[cur];
    const char* Vc = (const char*)Vt[cur];
    if (ch + 1 < NCHUNK) LOADR(ch + 1);   // in flight under the whole compute

    // S^T = K·Q^T fused with exp per 16-key tile (keeps s live-range at 8 regs)
    const bool lastch = (ch == NCHUNK-1);
    #pragma unroll
    for (int kt4 = 0; kt4 < 4; kt4++){
      f32x4 s0 = {}, s1 = {};
      #pragma unroll
      for (int ks = 0; ks < 2; ks++){
        hfrag kf = *(const hfrag*)(Kc + (kt4*16 + l16)*128
                                   + ((ks*64 + lq*16) ^ xk));
        s0 = __builtin_amdgcn_mfma_f32_16x16x32_f16(kf, qf[0][ks], s0, 0, 0, 0);
        s1 = __builtin_amdgcn_mfma_f32_16x16x32_f16(kf, qf[1][ks], s1, 0, 0, 0);
      }
      const int kb = kt4*16 + lq*4;
      #pragma unroll
      for (int qt = 0; qt < 2; qt++){
        const f32x4 sv = qt ? s1 : s0;
        float p0 = exp2_fast(sv[0] * temp);
        float p1 = exp2_fast(sv[1] * temp);
        float p2 = exp2_fast(sv[2] * temp);
        float p3 = exp2_fast(sv[3] * temp);
        if (lastch){
          if (kb + 0 >= LASTV) p0 = 0.f;
          if (kb + 1 >= LASTV) p1 = 0.f;
          if (kb + 2 >= LASTV) p2 = 0.f;
          if (kb + 3 >= LASTV) p3 = 0.f;
        }
        union { _Float16 hh[4]; i32x2 v2; } pw;
        pw.hh[0] = (_Float16)p0; pw.hh[1] = (_Float16)p1;
        pw.hh[2] = (_Float16)p2; pw.hh[3] = (_Float16)p3;
        *(i32x2*)((char*)Pt + (w*32 + qt*16 + l16)*128
                  + ((kt4*32 + lq*8) ^ xk)) = pw.v2;
      }
    }

    // PV: acc[qt][dt4] += P(queries) @ V; acc1[qt] += P @ ones (row sums)
    #pragma unroll
    for (int ks = 0; ks < 2; ks++){
      const int cb = (ks*64 + lq*16) ^ xk;
      hfrag pa0 = *(const hfrag*)((const char*)Pt + (w*32 +      l16)*128 + cb);
      hfrag pa1 = *(const hfrag*)((const char*)Pt + (w*32 + 16 + l16)*128 + cb);
      #pragma unroll
      for (int dt4 = 0; dt4 < 4; dt4++){
        hfrag vf = *(const hfrag*)(Vc + (dt4*16 + l16)*128 + cb);
        acc[0][dt4] = __builtin_amdgcn_mfma_f32_16x16x32_f16(pa0, vf, acc[0][dt4], 0, 0, 0);
        acc[1][dt4] = __builtin_amdgcn_mfma_f32_16x16x32_f16(pa1, vf, acc[1][dt4], 0, 0, 0);
      }
      acc1[0] = __builtin_amdgcn_mfma_f32_16x16x32_f16(pa0, ones, acc1[0], 0, 0, 0);
      acc1[1] = __builtin_amdgcn_mfma_f32_16x16x32_f16(pa1, ones, acc1[1], 0, 0, 0);
    }

    if (ch + 1 < NCHUNK){
      STORER(cur ^ 1);      // buf cur^1 last read in ch-1; barrier ordered it
      __syncthreads();      // writes visible; reads of cur done before reuse
    }
  }

  // epilogue: acc1[qt][r] already holds the full row sum in the owner lane
  #pragma unroll
  for (int qt = 0; qt < 2; qt++)
    #pragma unroll
    for (int r = 0; r < 4; r++){
      const int n = row0 + w*32 + qt*16 + lq*4 + r;
      if (n < NTOK){
        const float inv = 1.0f / acc1[qt][r];
        const size_t rbase = (size_t)(n*BB + b) * CC + h*HD;
        if (mode == 0){
          ushort_t* yo = (ushort_t*)outp;
          #pragma unroll
          for (int dt4 = 0; dt4 < 4; dt4++){
            union { _Float16 h16; ushort_t u; } cv;
            cv.h16 = (_Float16)(acc[qt][dt4][r] * inv);
            yo[rbase + dt4*16 + l16] = cv.u;
          }
        } else if (mode == 1){
          float* ao = (float*)outp;
          #pragma unroll
          for (int dt4 = 0; dt4 < 4; dt4++){
            float o = acc[qt][dt4][r] * inv;
            if (accum) o += ao[rbase + dt4*16 + l16];
            ao[rbase + dt4*16 + l16] = o;
          }
        } else {  // mode 2: (accin + own)/3 -> f16 out (replaces cvt pass)
          ushort_t* yo = (ushort_t*)outp;
          #pragma unroll
          for (int dt4 = 0; dt4 < 4; dt4++){
            const float o = (accin[rbase + dt4*16 + l16]
                             + acc[qt][dt4][r] * inv) * (1.0f/3.0f);
            union { _Float16 h16; ushort_t u; } cv;
            cv.h16 = (_Float16)o;
            yo[rbase + dt4*16 + l16] = cv.u;
          }
        }
      }
    }
}

// ---------------------------------------------------------------------------
extern "C" void kernel_launch(void* const* d_in, const int* in_sizes, int n_in,
                              void* d_out, int out_size, void* d_ws, size_t ws_size,
                              hipStream_t stream)
{
  (void)in_sizes; (void)n_in; (void)out_size; (void)ws_size;

  const float* x     = (const float*)d_in[0];   // fp32 [N,B,C]
  const float* wqkv  = (const float*)d_in[1];   // fp32 [2304,768]
  const float* wproj = (const float*)d_in[2];   // fp32 [768,768]
  const float* bias  = (const float*)d_in[3];   // fp32 [768]
  float* out = (float*)d_out;                   // fp32: [x_out | x_ori]

  ushort_t* x16  = (ushort_t*)d_ws;             // f16 [12552][768]
  ushort_t* wq16 = x16 + SZ;                    // f16 [2304][768]
  ushort_t* wp16 = wq16 + (size_t)2304*768;     // f16 [768][768]
  ushort_t* qb   = wp16 + (size_t)768*768;      // f16 [B,H,N,64] x3
  ushort_t* kb   = qb + SZ;
  ushort_t* vb   = kb + SZ;
  ushort_t* xh   = vb + SZ;                     // f16 [B,H,N,64] scratch
  ushort_t* y16  = xh + SZ;                     // f16 row-768 scratch
  float*    acc  = (float*)(y16 + SZ);          // fp32 row-768 accumulator
  float*    pre  = acc + SZ;                    // 8 floats

  hipMemsetAsync(pre, 0, BB * sizeof(float), stream);

  cvt_f16<<<(int)(SZ/8 + 255)/256, 256, 0, stream>>>(x, x16, (int)(SZ/8), 1.0f);
  cvt_f16<<<(2304*768/8 + 255)/256, 256, 0, stream>>>(wqkv, wq16, 2304*768/8, 1.0f);
  cvt_f16<<<(768*768/8 + 255)/256, 256, 0, stream>>>(wproj, wp16, 768*768/8, 1.0f);
  prenorm_kernel<<<dim3(50, 8), 256, 0, stream>>>(x, pre);

  gemm768<<<dim3(99, 18), 256, 0, stream>>>(x16, wq16, qb, kb, vb, nullptr, nullptr, 0);

  const float SCALE = 0.125f;                 // hd^-0.5
  const float FACT  = SCALE / (float)NTOK;    // inv_temp = pre[b] * FACT
  const dim3 AG(13, 96);

  // original attention -> x_ori (second output)
  attn_mfma<<<AG, 256, 0, stream>>>(qb, kb, vb, y16, nullptr, nullptr, SCALE, 0, 0);
  gemm768<<<dim3(99, 6), 256, 0, stream>>>(y16, wp16, nullptr, nullptr, nullptr,
      out + (size_t)NTOK * BB * CC, bias, 1);

  // self-self branches over {q, k, v}; last branch fuses (sum/3)->f16 into
  // its epilogue (mode 2) so no separate cvt pass is needed.
  const ushort_t* srcs[3] = { qb, kb, vb };
  for (int sI = 0; sI < 3; sI++){
    l2norm_kernel<<<NVEC/8, 256, 0, stream>>>(srcs[sI], xh, 0);
    attn_mfma<<<AG, 256, 0, stream>>>(xh, xh, xh, y16, nullptr, pre, FACT, 0, 0);
    l2norm_kernel<<<NVEC/8, 256, 0, stream>>>(y16, xh, 1);
    if (sI < 2)
      attn_mfma<<<AG, 256, 0, stream>>>(xh, xh, vb, acc, nullptr, pre, FACT, 1, sI == 0 ? 0 : 1);
    else
      attn_mfma<<<AG, 256, 0, stream>>>(xh, xh, vb, y16, acc, pre, FACT, 2, 1);
  }

  // proj -> x_out (first output)
  gemm768<<<dim3(99, 6), 256, 0, stream>>>(y16, wp16, nullptr, nullptr, nullptr,
      out, bias, 1);
}

// Round 12
// 1027.202 us; speedup vs baseline: 2.0097x; 1.0601x over previous
//
#include <hip/hip_runtime.h>
#include <stdint.h>

#define NTOK 1569
#define BB 8
#define CC 768
#define HH 12
#define HD 64
#define NBH (BB*HH)          // 96
#define NROW (NTOK*BB)       // 12552 rows of the [N*B][768] matrices
#define NCHUNK 25            // ceil(1569/64) key chunks
#define NVEC (NBH*NTOK)      // 150624 head-vectors
#define LASTV 33             // valid keys in last chunk: 1569 - 24*64

typedef unsigned short ushort_t;
static const size_t SZ = (size_t)NROW * CC;   // 9,639,936 elems (= NBH*NTOK*HD)

using f32x4 = __attribute__((ext_vector_type(4))) float;
using i32x4 = __attribute__((ext_vector_type(4))) int;
using i32x2 = __attribute__((ext_vector_type(2))) int;
using hfrag = __attribute__((ext_vector_type(8))) _Float16;

// v_exp_f32 computes 2^x; temp is pre-scaled by log2(e) so one trans op/elem.
__device__ __forceinline__ float exp2_fast(float x){
  float r;
  asm("v_exp_f32 %0, %1" : "=v"(r) : "v"(x));
  return r;
}

// ---------------------------------------------------------------------------
// pre[b] = sum_n ||x[n,b,:]||_2  (fp32 input)
// ---------------------------------------------------------------------------
__global__ __launch_bounds__(256) void prenorm_kernel(const float* __restrict__ x,
                                                      float* __restrict__ pre)
{
  const int b = blockIdx.y;
  const int wave = threadIdx.x >> 6, lane = threadIdx.x & 63;
  const int g = blockIdx.x * 4 + wave;          // [0, 200)
  float local = 0.f;
  for (int n = g; n < NTOK; n += 200){
    const float* xp = x + ((size_t)n * BB + b) * CC + lane * 4;
    float ss = 0.f;
    #pragma unroll
    for (int e = 0; e < 3; e++){
      f32x4 vv = *(const f32x4*)(xp + 256*e);
      ss += vv[0]*vv[0] + vv[1]*vv[1] + vv[2]*vv[2] + vv[3]*vv[3];
    }
    #pragma unroll
    for (int off = 1; off < 64; off <<= 1) ss += __shfl_xor(ss, off);
    local += sqrtf(ss);
  }
  if (lane == 0) atomicAdd(&pre[b], local);
}

// ---------------------------------------------------------------------------
// elementwise fp32 -> f16 (RTN), optional scale; n8 = elems/8
// ---------------------------------------------------------------------------
__global__ __launch_bounds__(256) void cvt_f16(const float* __restrict__ in,
                                               ushort_t* __restrict__ out,
                                               int n8, float scl)
{
  const int i = blockIdx.x * 256 + threadIdx.x;
  if (i >= n8) return;
  const float* p = in + (size_t)i * 8;
  f32x4 a = *(const f32x4*)p, b = *(const f32x4*)(p + 4);
  union { _Float16 h[8]; i32x4 v; } u;
  #pragma unroll
  for (int e = 0; e < 4; e++){
    u.h[e]   = (_Float16)(a[e] * scl);
    u.h[4+e] = (_Float16)(b[e] * scl);
  }
  *(i32x4*)(out + (size_t)i * 8) = u.v;
}

// ---------------------------------------------------------------------------
// f16 GEMM: C[m][j] = sum_c A[m][c] * B[j][c];  A [12552][768], B [Nj][768].
// 128x128 tile, BK=64. R10/R11 (validated): staging via global_load_lds
// width=16; LDS linear in 16B chunks, swizzle moved to the SOURCE (rule #21):
// lane reads colblk (lane&7)^(lane>>3); compute reads XOR the same key.
// mode 0: scatter f16 to q/k/v [B,H,N,64] (Nj=2304)
// mode 1: fp32 out[m*768 + j] + bias[j]       (Nj=768)
// grid: (99, Nj/128), block 256.  XCD remap (R8, validated).
// ---------------------------------------------------------------------------
__global__ __launch_bounds__(256) void gemm768(
    const ushort_t* __restrict__ A, const ushort_t* __restrict__ Bm,
    ushort_t* __restrict__ q, ushort_t* __restrict__ k, ushort_t* __restrict__ v,
    float* __restrict__ outp, const float* __restrict__ bias, int mode)
{
  __shared__ __align__(16) ushort_t As[8192];  // [row 0..127][cb 0..7][8], cb swizzled
  __shared__ __align__(16) ushort_t Bs[8192];

  // XCD-aware remap: lin -> (mt, jt), jt fastest within each XCD chunk
  const int jtN = gridDim.y;
  const int lin = blockIdx.y * 99 + blockIdx.x;
  const int T  = 99 * jtN;
  const int qq = T >> 3, rr = T & 7;
  const int c  = lin & 7, ii = lin >> 3;
  const int start = c*qq + (c < rr ? c : rr);
  const int idx = start + ii;
  const int mt = idx / jtN, jt = idx - mt*jtN;

  const int tid = threadIdx.x;
  const int w = tid >> 6, lane = tid & 63;
  const int l16 = lane & 15, lq = lane >> 4;

  // staging source map: lane -> (row-quad, swizzled colblk)
  const int rquad = lane >> 3;                 // 0..7
  const int kqs   = (lane & 7) ^ rquad;        // source colblk (inverse swz)
  const ushort_t* apb[4];
  const ushort_t* bpb[4];
  #pragma unroll
  for (int i = 0; i < 4; i++){
    int ar = mt*128 + i*32 + w*8 + rquad; if (ar > NROW-1) ar = NROW-1;
    apb[i] = A + (size_t)ar*CC + kqs*8;
    const int br = jt*128 + i*32 + w*8 + rquad;
    bpb[i] = Bm + (size_t)br*CC + kqs*8;
  }

  const int wr = (w >> 1) * 4, wc = (w & 1) * 4;      // 16-row/col block bases
  const int rx = l16 & 7;                             // read-side swizzle key

  f32x4 acc[4][4] = {};
  for (int kt = 0; kt < 12; kt++){
    #pragma unroll
    for (int i = 0; i < 4; i++){
      __builtin_amdgcn_global_load_lds(
          (const __attribute__((address_space(1))) void*)apb[i],
          (__attribute__((address_space(3))) void*)&As[(i*256 + w*64)*8],
          16, 0, 0);
      __builtin_amdgcn_global_load_lds(
          (const __attribute__((address_space(1))) void*)bpb[i],
          (__attribute__((address_space(3))) void*)&Bs[(i*256 + w*64)*8],
          16, 0, 0);
      apb[i] += 64; bpb[i] += 64;
    }
    __syncthreads();   // compiler drains vmcnt before barrier (m97 structure)
    #pragma unroll
    for (int ks = 0; ks < 2; ks++){
      hfrag af[4], bf[4];
      #pragma unroll
      for (int rt = 0; rt < 4; rt++)
        af[rt] = *(const hfrag*)((const char*)As
                   + ((wr+rt)*16 + l16)*128 + ((((ks*4+lq) ^ rx)) << 4));
      #pragma unroll
      for (int ct = 0; ct < 4; ct++)
        bf[ct] = *(const hfrag*)((const char*)Bs
                   + ((wc+ct)*16 + l16)*128 + ((((ks*4+lq) ^ rx)) << 4));
      #pragma unroll
      for (int rt = 0; rt < 4; rt++)
        #pragma unroll
        for (int ct = 0; ct < 4; ct++)
          acc[rt][ct] = __builtin_amdgcn_mfma_f32_16x16x32_f16(af[rt], bf[ct], acc[rt][ct], 0, 0, 0);
    }
    __syncthreads();
  }

  const int mbase = mt*128 + (w >> 1)*64;
  const int jbase = jt*128 + (w & 1)*64;
  #pragma unroll
  for (int ct = 0; ct < 4; ct++){
    const int j = jbase + ct*16 + l16;
    if (mode == 0){
      const int s = j / 768, jj = j - s*768;
      const int h = jj >> 6, d = jj & 63;
      ushort_t* op = (s == 0) ? q : (s == 1) ? k : v;
      #pragma unroll
      for (int rt = 0; rt < 4; rt++)
        #pragma unroll
        for (int r = 0; r < 4; r++){
          const int m = mbase + rt*16 + lq*4 + r;
          if (m < NROW){
            const int n = m >> 3, b = m & 7;
            union { _Float16 h16; ushort_t u; } cv;
            cv.h16 = (_Float16)acc[rt][ct][r];
            op[((size_t)(b*HH + h) * NTOK + n) * HD + d] = cv.u;
          }
        }
    } else {
      const float bv = bias[j];
      #pragma unroll
      for (int rt = 0; rt < 4; rt++)
        #pragma unroll
        for (int r = 0; r < 4; r++){
          const int m = mbase + rt*16 + lq*4 + r;
          if (m < NROW) outp[(size_t)m * CC + j] = acc[rt][ct][r] + bv;
        }
    }
  }
}

// ---------------------------------------------------------------------------
// l2 normalize per head-vector (64 elems), 32 lanes/vector, f16 in/out.
// mode 0: in is [B,H,N,64] (mode 1 path retained but unused since R12).
// out: [B,H,N,64]
// ---------------------------------------------------------------------------
__global__ __launch_bounds__(256) void l2norm_kernel(const ushort_t* __restrict__ in,
                                                     ushort_t* __restrict__ out,
                                                     int mode)
{
  const int vec = blockIdx.x * 8 + (threadIdx.x >> 5);
  const int lane = threadIdx.x & 31;
  if (vec >= NVEC) return;
  size_t iaddr;
  if (mode == 0){
    iaddr = (size_t)vec * HD + lane*2;
  } else {
    const int b = vec / (HH*NTOK);
    const int rem = vec - b*(HH*NTOK);
    const int h = rem / NTOK, n = rem - h*NTOK;
    iaddr = (size_t)(n*BB + b) * CC + h*HD + lane*2;
  }
  union { ushort_t u[2]; uint32_t pk; _Float16 h[2]; } uv;
  uv.pk = *(const uint32_t*)(in + iaddr);
  const float a = (float)uv.h[0], c = (float)uv.h[1];
  float ss = a*a + c*c;
  #pragma unroll
  for (int off = 1; off < 32; off <<= 1) ss += __shfl_xor(ss, off);
  const float inv = 1.0f / fmaxf(sqrtf(ss), 1e-12f);
  union { _Float16 h[2]; uint32_t pk; } ov;
  ov.h[0] = (_Float16)(a * inv);
  ov.h[1] = (_Float16)(c * inv);
  *(uint32_t*)(out + (size_t)vec * HD + lane*2) = ov.pk;
}

// ---------------------------------------------------------------------------
// MFMA flash attention, transposed-S, max-free softmax (logits provably small).
// X,Y,Z f16 [B,H,N,64]. 128 queries/block (4 waves x 32), 64-key chunks.
//
// R12: mode 3 — fused l2norm epilogue for the branch attn1 calls. l2norm is
// scale-invariant, so normalize(acc * inv_softmax) = acc / ||acc||: skip the
// softmax division AND the separate l2norm(mode 1) pass. Each 16-lane l16
// group holds a query's full 64 d values -> 4 shfl_xor reduce + rsqrt, once
// per kernel. mode 3 also skips the acc1 ones-MFMAs (-4 MFMA/chunk).
// Output BHND f16. Removes 3 l2norm dispatches (+their 38MB traffic each).
// R9-R11 (validated): MFMA row-sums, dbuf 1-barrier, T14 prefetch,
// static-index V repack, XOR swizzle, XCD remap, exp2 direct.
// LDS: Ks 2x8K + Vt 2x8K + Pt 16K = 48 KiB.  grid: (13, 96)
// ---------------------------------------------------------------------------
__global__ __launch_bounds__(256) void attn_mfma(
    const ushort_t* __restrict__ X, const ushort_t* __restrict__ Y,
    const ushort_t* __restrict__ Z, void* __restrict__ outp,
    const float* __restrict__ accin,
    const float* __restrict__ pre, float tf, int mode, int accum)
{
  __shared__ __align__(16) ushort_t Ks[2][64*64];   // [key][d], swizzled
  __shared__ __align__(16) ushort_t Vt[2][64*64];   // [d][key], swizzled
  __shared__ __align__(16) ushort_t Pt[128*64];     // [q][key], swizzled

  // XCD-aware remap (bijective: 1248 = 8*156, 156 = 12*13)
  const int lin  = blockIdx.y * 13 + blockIdx.x;
  const int nl   = (lin & 7) * 156 + (lin >> 3);
  const int bh   = nl / 13;
  const int qblk = nl - bh * 13;

  const int b = bh / HH, h = bh - (bh / HH) * HH;
  const float temp = (pre ? pre[b] * tf : tf) * 1.4426950408889634f;
  const size_t base = (size_t)bh * NTOK * HD;
  const int row0 = qblk * 128;
  const int tid = threadIdx.x;
  const int w = tid >> 6, lane = tid & 63;
  const int l16 = lane & 15, lq = lane >> 4;
  const int xk = (l16 & 7) << 4;                 // swizzle key for compute reads
  const bool needsum = (mode != 3);              // mode 3 normalizes by ||acc||

  // Q fragments (b-operand of S^T): rows row0 + w*32 + qt*16 + l16
  hfrag qf[2][2];
  #pragma unroll
  for (int qt = 0; qt < 2; qt++){
    int r = row0 + w*32 + qt*16 + l16; if (r > NTOK-1) r = NTOK-1;
    const ushort_t* qp = X + base + (size_t)r*HD + lq*8;
    qf[qt][0] = *(const hfrag*)qp;
    qf[qt][1] = *(const hfrag*)(qp + 32);
  }

  hfrag ones;
  #pragma unroll
  for (int e = 0; e < 8; e++) ones[e] = (_Float16)1.0f;

  // staging maps
  const int skey = tid & 63, sseg = tid >> 6;              // K natural
  const int kx = (skey & 7) << 4;
  const int vd2 = (tid & 31) * 2;                          // V^T: row pair base
  const int vko = (tid >> 5) * 8;                          //      key octet

  // prefetch registers (static-indexed only; rule #20)
  i32x4 kr0, kr1;
  uint32_t L[8];

  auto LOADR = [&](int ch){
    int kg = ch*64 + skey; if (kg > NTOK-1) kg = NTOK-1;
    const ushort_t* kp = Y + base + (size_t)kg*HD + sseg*16;
    kr0 = *(const i32x4*)kp;
    kr1 = *(const i32x4*)(kp + 8);
    #pragma unroll
    for (int j = 0; j < 8; j++){
      int vg = ch*64 + vko + j; if (vg > NTOK-1) vg = NTOK-1;
      L[j] = *(const uint32_t*)(Z + base + (size_t)vg*HD + vd2);
    }
  };
  auto STORER = [&](int bf){
    char* kbp = (char*)Ks[bf] + skey*128;
    *(i32x4*)(kbp + ((sseg*32     ) ^ kx)) = kr0;
    *(i32x4*)(kbp + ((sseg*32 + 16) ^ kx)) = kr1;
    i32x4 vlo, vhi;
    #pragma unroll
    for (int cc = 0; cc < 4; cc++){
      const uint32_t Aw = L[2*cc], Bw = L[2*cc+1];
      vlo[cc] = (int)((Aw & 0xffffu) | (Bw << 16));
      vhi[cc] = (int)((Aw >> 16) | (Bw & 0xffff0000u));
    }
    char* vbp = (char*)Vt[bf];
    *(i32x4*)(vbp + vd2*128     + ((vko*2) ^ ((vd2 & 7) << 4)))     = vlo;
    *(i32x4*)(vbp + (vd2+1)*128 + ((vko*2) ^ (((vd2+1) & 7) << 4))) = vhi;
  };

  f32x4 acc[2][4] = {};     // [qt][dt4], rows=queries(4lq+r), cols=d(l16)
  f32x4 acc1[2] = {};       // row sums: sum_k P, same row mapping, any col

  LOADR(0);
  STORER(0);
  __syncthreads();

  for (int ch = 0; ch < NCHUNK; ch++){
    const int cur = ch & 1;
    const char* Kc = (const char*)Ks[cur];
    const char* Vc = (const char*)Vt[cur];
    if (ch + 1 < NCHUNK) LOADR(ch + 1);   // in flight under the whole compute

    // S^T = K·Q^T fused with exp per 16-key tile (keeps s live-range at 8 regs)
    const bool lastch = (ch == NCHUNK-1);
    #pragma unroll
    for (int kt4 = 0; kt4 < 4; kt4++){
      f32x4 s0 = {}, s1 = {};
      #pragma unroll
      for (int ks = 0; ks < 2; ks++){
        hfrag kf = *(const hfrag*)(Kc + (kt4*16 + l16)*128
                                   + ((ks*64 + lq*16) ^ xk));
        s0 = __builtin_amdgcn_mfma_f32_16x16x32_f16(kf, qf[0][ks], s0, 0, 0, 0);
        s1 = __builtin_amdgcn_mfma_f32_16x16x32_f16(kf, qf[1][ks], s1, 0, 0, 0);
      }
      const int kb = kt4*16 + lq*4;
      #pragma unroll
      for (int qt = 0; qt < 2; qt++){
        const f32x4 sv = qt ? s1 : s0;
        float p0 = exp2_fast(sv[0] * temp);
        float p1 = exp2_fast(sv[1] * temp);
        float p2 = exp2_fast(sv[2] * temp);
        float p3 = exp2_fast(sv[3] * temp);
        if (lastch){
          if (kb + 0 >= LASTV) p0 = 0.f;
          if (kb + 1 >= LASTV) p1 = 0.f;
          if (kb + 2 >= LASTV) p2 = 0.f;
          if (kb + 3 >= LASTV) p3 = 0.f;
        }
        union { _Float16 hh[4]; i32x2 v2; } pw;
        pw.hh[0] = (_Float16)p0; pw.hh[1] = (_Float16)p1;
        pw.hh[2] = (_Float16)p2; pw.hh[3] = (_Float16)p3;
        *(i32x2*)((char*)Pt + (w*32 + qt*16 + l16)*128
                  + ((kt4*32 + lq*8) ^ xk)) = pw.v2;
      }
    }

    // PV: acc[qt][dt4] += P(queries) @ V; acc1[qt] += P @ ones (row sums)
    #pragma unroll
    for (int ks = 0; ks < 2; ks++){
      const int cb = (ks*64 + lq*16) ^ xk;
      hfrag pa0 = *(const hfrag*)((const char*)Pt + (w*32 +      l16)*128 + cb);
      hfrag pa1 = *(const hfrag*)((const char*)Pt + (w*32 + 16 + l16)*128 + cb);
      #pragma unroll
      for (int dt4 = 0; dt4 < 4; dt4++){
        hfrag vf = *(const hfrag*)(Vc + (dt4*16 + l16)*128 + cb);
        acc[0][dt4] = __builtin_amdgcn_mfma_f32_16x16x32_f16(pa0, vf, acc[0][dt4], 0, 0, 0);
        acc[1][dt4] = __builtin_amdgcn_mfma_f32_16x16x32_f16(pa1, vf, acc[1][dt4], 0, 0, 0);
      }
      if (needsum){
        acc1[0] = __builtin_amdgcn_mfma_f32_16x16x32_f16(pa0, ones, acc1[0], 0, 0, 0);
        acc1[1] = __builtin_amdgcn_mfma_f32_16x16x32_f16(pa1, ones, acc1[1], 0, 0, 0);
      }
    }

    if (ch + 1 < NCHUNK){
      STORER(cur ^ 1);      // buf cur^1 last read in ch-1; barrier ordered it
      __syncthreads();      // writes visible; reads of cur done before reuse
    }
  }

  // epilogue
  #pragma unroll
  for (int qt = 0; qt < 2; qt++)
    #pragma unroll
    for (int r = 0; r < 4; r++){
      const int n = row0 + w*32 + qt*16 + lq*4 + r;
      if (mode == 3){
        // fused l2norm: ss over 64 d (4 dt4 here x 16 l16 lanes); softmax
        // scale cancels (x/||x|| invariant). All lanes join the shfl.
        float ss = 0.f;
        #pragma unroll
        for (int dt4 = 0; dt4 < 4; dt4++)
          ss += acc[qt][dt4][r] * acc[qt][dt4][r];
        ss += __shfl_xor(ss, 1);
        ss += __shfl_xor(ss, 2);
        ss += __shfl_xor(ss, 4);
        ss += __shfl_xor(ss, 8);
        const float inv = 1.0f / fmaxf(sqrtf(ss), 1e-12f);
        if (n < NTOK){
          ushort_t* yo = (ushort_t*)outp;
          const size_t obase = (base + (size_t)n*HD);
          #pragma unroll
          for (int dt4 = 0; dt4 < 4; dt4++){
            union { _Float16 h16; ushort_t u; } cv;
            cv.h16 = (_Float16)(acc[qt][dt4][r] * inv);
            yo[obase + dt4*16 + l16] = cv.u;
          }
        }
        continue;
      }
      if (n < NTOK){
        const float inv = 1.0f / acc1[qt][r];
        const size_t rbase = (size_t)(n*BB + b) * CC + h*HD;
        if (mode == 0){
          ushort_t* yo = (ushort_t*)outp;
          #pragma unroll
          for (int dt4 = 0; dt4 < 4; dt4++){
            union { _Float16 h16; ushort_t u; } cv;
            cv.h16 = (_Float16)(acc[qt][dt4][r] * inv);
            yo[rbase + dt4*16 + l16] = cv.u;
          }
        } else if (mode == 1){
          float* ao = (float*)outp;
          #pragma unroll
          for (int dt4 = 0; dt4 < 4; dt4++){
            float o = acc[qt][dt4][r] * inv;
            if (accum) o += ao[rbase + dt4*16 + l16];
            ao[rbase + dt4*16 + l16] = o;
          }
        } else {  // mode 2: (accin + own)/3 -> f16 out (replaces cvt pass)
          ushort_t* yo = (ushort_t*)outp;
          #pragma unroll
          for (int dt4 = 0; dt4 < 4; dt4++){
            const float o = (accin[rbase + dt4*16 + l16]
                             + acc[qt][dt4][r] * inv) * (1.0f/3.0f);
            union { _Float16 h16; ushort_t u; } cv;
            cv.h16 = (_Float16)o;
            yo[rbase + dt4*16 + l16] = cv.u;
          }
        }
      }
    }
}

// ---------------------------------------------------------------------------
extern "C" void kernel_launch(void* const* d_in, const int* in_sizes, int n_in,
                              void* d_out, int out_size, void* d_ws, size_t ws_size,
                              hipStream_t stream)
{
  (void)in_sizes; (void)n_in; (void)out_size; (void)ws_size;

  const float* x     = (const float*)d_in[0];   // fp32 [N,B,C]
  const float* wqkv  = (const float*)d_in[1];   // fp32 [2304,768]
  const float* wproj = (const float*)d_in[2];   // fp32 [768,768]
  const float* bias  = (const float*)d_in[3];   // fp32 [768]
  float* out = (float*)d_out;                   // fp32: [x_out | x_ori]

  ushort_t* x16  = (ushort_t*)d_ws;             // f16 [12552][768]
  ushort_t* wq16 = x16 + SZ;                    // f16 [2304][768]
  ushort_t* wp16 = wq16 + (size_t)2304*768;     // f16 [768][768]
  ushort_t* qb   = wp16 + (size_t)768*768;      // f16 [B,H,N,64] x3
  ushort_t* kb   = qb + SZ;
  ushort_t* vb   = kb + SZ;
  ushort_t* xh   = vb + SZ;                     // f16 [B,H,N,64] scratch
  ushort_t* y16  = xh + SZ;                     // f16 scratch (BHND or row-768)
  float*    acc  = (float*)(y16 + SZ);          // fp32 row-768 accumulator
  float*    pre  = acc + SZ;                    // 8 floats

  hipMemsetAsync(pre, 0, BB * sizeof(float), stream);

  cvt_f16<<<(int)(SZ/8 + 255)/256, 256, 0, stream>>>(x, x16, (int)(SZ/8), 1.0f);
  cvt_f16<<<(2304*768/8 + 255)/256, 256, 0, stream>>>(wqkv, wq16, 2304*768/8, 1.0f);
  cvt_f16<<<(768*768/8 + 255)/256, 256, 0, stream>>>(wproj, wp16, 768*768/8, 1.0f);
  prenorm_kernel<<<dim3(50, 8), 256, 0, stream>>>(x, pre);

  gemm768<<<dim3(99, 18), 256, 0, stream>>>(x16, wq16, qb, kb, vb, nullptr, nullptr, 0);

  const float SCALE = 0.125f;                 // hd^-0.5
  const float FACT  = SCALE / (float)NTOK;    // inv_temp = pre[b] * FACT
  const dim3 AG(13, 96);

  // original attention -> x_ori (second output)
  attn_mfma<<<AG, 256, 0, stream>>>(qb, kb, vb, y16, nullptr, nullptr, SCALE, 0, 0);
  gemm768<<<dim3(99, 6), 256, 0, stream>>>(y16, wp16, nullptr, nullptr, nullptr,
      out + (size_t)NTOK * BB * CC, bias, 1);

  // self-self branches over {q, k, v}. attn1 runs mode 3 (fused l2norm,
  // BHND out) so the separate l2norm mode-1 pass is gone. Buffer routing:
  // sI 0,1 -> y16 (free until sI=2); sI 2 -> qb (dead after sI=0's l2norm;
  // cannot write y16 there since attn2 mode 2 writes y16 while reading X).
  const ushort_t* srcs[3] = { qb, kb, vb };
  for (int sI = 0; sI < 3; sI++){
    l2norm_kernel<<<NVEC/8, 256, 0, stream>>>(srcs[sI], xh, 0);
    ushort_t* n1 = (sI < 2) ? y16 : qb;
    attn_mfma<<<AG, 256, 0, stream>>>(xh, xh, xh, n1, nullptr, pre, FACT, 3, 0);
    if (sI < 2)
      attn_mfma<<<AG, 256, 0, stream>>>(n1, n1, vb, acc, nullptr, pre, FACT, 1, sI == 0 ? 0 : 1);
    else
      attn_mfma<<<AG, 256, 0, stream>>>(n1, n1, vb, y16, acc, pre, FACT, 2, 1);
  }

  // proj -> x_out (first output)
  gemm768<<<dim3(99, 6), 256, 0, stream>>>(y16, wp16, nullptr, nullptr, nullptr,
      out, bias, 1);
}